// Round 13
// baseline (552.117 us; speedup 1.0000x reference)
//
#include <hip/hip_runtime.h>
#include <math.h>

#define NS 1024
#define T0 32
#define DF 158
#define DG 63
#define DM 256
#define XROW (DF + DG)  // 221
// merged-scale row bases: h0 rows [0,32768), h1 [32768,49152), h2 [49152,57344)
#define MTOT 57344
#define B1R 32768
#define B2R 49152

typedef unsigned short u16;
typedef __attribute__((ext_vector_type(8))) short bf16x8_t;
typedef __attribute__((ext_vector_type(4))) float f32x4_t;

union frag_u {
  bf16x8_t f;
  unsigned short us[8];
  unsigned int u32[4];
};

__device__ inline unsigned short f2bf(float x) {
  unsigned int u = __float_as_uint(x);
  unsigned int r = u + 0x7fffu + ((u >> 16) & 1u);
  return (unsigned short)(r >> 16);
}
__device__ inline float bf2f(u16 u) {
  return __uint_as_float(((unsigned int)u) << 16);
}
// v_cvt_pk_bf16_f32: D.lo16 = bf16(a), D.hi16 = bf16(b)
__device__ inline unsigned int cvtpk(float a, float b) {
  unsigned int r;
  asm("v_cvt_pk_bf16_f32 %0, %1, %2" : "=v"(r) : "v"(a), "v"(b));
  return r;
}
// async global->LDS, 16B per lane; LDS dest must be lane-linear (wave-uniform base + lane*16)
__device__ inline void gl16(const u16* gp, unsigned char* lp) {
  __builtin_amdgcn_global_load_lds((const __attribute__((address_space(1))) unsigned int*)gp,
                                   (__attribute__((address_space(3))) unsigned int*)lp, 16, 0, 0);
}

// ---------------- positional encoding table (32 x 256) ----------------
__global__ void k_pe(float* __restrict__ pe) {
  int t = blockIdx.x, d = threadIdx.x;
  int i2 = d & ~1;
  float div = expf((float)i2 * (-logf(10000.0f) / (float)DM));
  float ang = (float)t * div;
  pe[t * DM + d] = (d & 1) ? cosf(ang) : sinf(ang);
}

// ---------------- gate ----------------
__global__ void k_gate(const float* __restrict__ x, const float* __restrict__ gW,
                       const float* __restrict__ gb, float* __restrict__ g) {
  int n = blockIdx.x, tid = threadIdx.x;
  __shared__ float gin[DG];
  __shared__ float red[256];
  if (tid < DG) gin[tid] = x[(size_t)n * T0 * XROW + 31 * XROW + DF + tid];
  __syncthreads();
  float myv = 0.f;
  if (tid < DF) {
    float acc = gb[tid];
    for (int j = 0; j < DG; j++) acc = fmaf(gin[j], gW[j * DF + tid], acc);
    myv = acc * (1.0f / 5.0f);
  }
  red[tid] = (tid < DF) ? myv : -1e30f;
  __syncthreads();
  for (int s = 128; s > 0; s >>= 1) { if (tid < s) red[tid] = fmaxf(red[tid], red[tid + s]); __syncthreads(); }
  float mx = red[0];
  __syncthreads();
  float e = (tid < DF) ? expf(myv - mx) : 0.f;
  red[tid] = e;
  __syncthreads();
  for (int s = 128; s > 0; s >>= 1) { if (tid < s) red[tid] += red[tid + s]; __syncthreads(); }
  float sum = red[0];
  if (tid < DF) g[(size_t)n * DF + tid] = (float)DF * e / sum;
}

// ---------------- weight prep: W[K][256] fp32 -> Wt[256][256] bf16 (transposed, scaled, zero-pad K) ----------------
struct WPrep { const float* s[14]; float sc[14]; };
__global__ __launch_bounds__(256) void k_wprep(WPrep w, u16* __restrict__ dst) {
  int mat = blockIdx.x >> 4, nb = blockIdx.x & 15;
  int tid = threadIdx.x;
  int n = nb * 16 + (tid >> 4);
  int kc = (tid & 15) * 16;
  const float* src = w.s[mat];
  float sc = w.sc[mat];
  int K = (mat == 0) ? DF : 256;
  frag_u f0, f1;
#pragma unroll
  for (int j = 0; j < 8; j++) {
    int k0 = kc + j, k1 = kc + 8 + j;
    f0.us[j] = (k0 < K) ? f2bf(src[(size_t)k0 * 256 + n] * sc) : (u16)0;
    f1.us[j] = (k1 < K) ? f2bf(src[(size_t)k1 * 256 + n] * sc) : (u16)0;
  }
  u16* d = dst + (size_t)mat * 65536 + (size_t)n * 256 + kc;
  *(bf16x8_t*)d = f0.f;
  *(bf16x8_t*)(d + 8) = f1.f;
}

// ---------------- fus_W transpose: [768][256] fp32 -> [256][768] bf16 ----------------
__global__ __launch_bounds__(256) void k_wtrans(const float* __restrict__ W, u16* __restrict__ Wt) {
  __shared__ u16 Ts[64][65];
  int k0 = blockIdx.x * 64, n0 = blockIdx.y * 64;
  int tid = threadIdx.x;
#pragma unroll
  for (int i = 0; i < 16; i++) {
    int e = tid + i * 256;
    int r = e >> 6, c = e & 63;
    Ts[r][c] = f2bf(W[(size_t)(k0 + r) * 256 + n0 + c]);
  }
  __syncthreads();
#pragma unroll
  for (int i = 0; i < 16; i++) {
    int e = tid + i * 256;
    int r = e >> 6, c = e & 63;
    Wt[(size_t)(n0 + r) * 768 + k0 + c] = Ts[c][r];
  }
}

// ---------------- bf16 MFMA GEMM (round-6 proven): gl16 staging, 32KB LDS ----------------
template <bool BIAS, bool RELU, bool RES, bool OUTBF>
__global__ __launch_bounds__(256) void k_bgemm(
    const u16* __restrict__ A,
    const u16* __restrict__ B0, const u16* __restrict__ B1, const u16* __restrict__ B2,
    const float* __restrict__ bias, const u16* __restrict__ res,
    void* __restrict__ C0, void* __restrict__ C1, void* __restrict__ C2) {
  __shared__ __align__(16) unsigned char sm[32768];
  unsigned char* As = sm;
  unsigned char* Bs = sm + 16384;
  const u16* Bt = blockIdx.z == 0 ? B0 : (blockIdx.z == 1 ? B1 : B2);
  void* Cv = blockIdx.z == 0 ? C0 : (blockIdx.z == 1 ? C1 : C2);
  int m0 = blockIdx.y * 128, n0w = blockIdx.x * 128;
  int tid = threadIdx.x, lane = tid & 63, wid = tid >> 6;
  int qi = lane & 15, g = lane >> 4;
  int wr = wid >> 1, wc = wid & 1;
  f32x4_t acc[4][4];
#pragma unroll
  for (int i = 0; i < 4; i++)
#pragma unroll
    for (int j = 0; j < 4; j++) acc[i][j] = (f32x4_t){0.f, 0.f, 0.f, 0.f};
  for (int kt = 0; kt < 4; kt++) {
    if (kt) __syncthreads();
    // stage via global_load_lds: LDS lane-linear, global source pre-swizzled (c^(row&7))
#pragma unroll
    for (int i = 0; i < 4; i++) {
      int cid = tid + i * 256;
      int row = cid >> 3, c = cid & 7;
      int cs = c ^ (row & 7);
      gl16(A + (size_t)(m0 + row) * 256 + kt * 64 + cs * 8, As + cid * 16);
      gl16(Bt + (size_t)(n0w + row) * 256 + kt * 64 + cs * 8, Bs + cid * 16);
    }
    __syncthreads();
    bf16x8_t Af[2][4], Bf[2][4];
#pragma unroll
    for (int mi = 0; mi < 4; mi++) {
      int row = wr * 64 + mi * 16 + qi;
      int swz = (row & 7) << 4;
      const unsigned char* ap = As + row * 128;
      Af[0][mi] = *(const bf16x8_t*)(ap + ((g * 16) ^ swz));
      Af[1][mi] = *(const bf16x8_t*)(ap + ((64 + g * 16) ^ swz));
    }
#pragma unroll
    for (int ni = 0; ni < 4; ni++) {
      int row = wc * 64 + ni * 16 + qi;
      int swz = (row & 7) << 4;
      const unsigned char* bp = Bs + row * 128;
      Bf[0][ni] = *(const bf16x8_t*)(bp + ((g * 16) ^ swz));
      Bf[1][ni] = *(const bf16x8_t*)(bp + ((64 + g * 16) ^ swz));
    }
#pragma unroll
    for (int ks = 0; ks < 2; ks++)
#pragma unroll
      for (int mi = 0; mi < 4; mi++)
#pragma unroll
        for (int ni = 0; ni < 4; ni++)
          acc[mi][ni] = __builtin_amdgcn_mfma_f32_16x16x32_bf16(Af[ks][mi], Bf[ks][ni], acc[mi][ni], 0, 0, 0);
  }
#pragma unroll
  for (int mi = 0; mi < 4; mi++) {
#pragma unroll
    for (int ni = 0; ni < 4; ni++) {
#pragma unroll
      for (int r = 0; r < 4; r++) {
        int row = m0 + wr * 64 + mi * 16 + 4 * g + r;
        int col = n0w + wc * 64 + ni * 16 + qi;
        float vv = acc[mi][ni][r];
        if (BIAS) vv += bias[col];
        if (RES) vv += bf2f(res[(size_t)row * 256 + col]);
        if (RELU) vv = fmaxf(vv, 0.f);
        if (OUTBF) ((u16*)Cv)[(size_t)row * 256 + col] = f2bf(vv);
        else ((float*)Cv)[(size_t)row * 256 + col] = vv;
      }
    }
  }
}

// ---------------- feat GEMM: h = (x*gate)@feat_W + bias + pe, fp32 out ----------------
__global__ __launch_bounds__(256) void k_fgemm(
    const float* __restrict__ x, const float* __restrict__ gate,
    const u16* __restrict__ Bt, const float* __restrict__ bias,
    const float* __restrict__ pe, float* __restrict__ C) {
  __shared__ __align__(16) unsigned char sm[32768];
  unsigned char* As = sm;
  unsigned char* Bs = sm + 16384;
  int m0 = blockIdx.y * 128, n0w = blockIdx.x * 128;
  int tid = threadIdx.x, lane = tid & 63, wid = tid >> 6;
  int qi = lane & 15, g = lane >> 4;
  int wr = wid >> 1, wc = wid & 1;
  f32x4_t acc[4][4];
#pragma unroll
  for (int i = 0; i < 4; i++)
#pragma unroll
    for (int j = 0; j < 4; j++) acc[i][j] = (f32x4_t){0.f, 0.f, 0.f, 0.f};
  for (int kt = 0; kt < 3; kt++) {
    if (kt) __syncthreads();
#pragma unroll
    for (int i = 0; i < 4; i++) {
      int cid = tid + i * 256;
      int row = cid >> 3, c = cid & 7;
      int swz = (c * 16) ^ ((row & 7) << 4);
      int gk0 = kt * 64 + c * 8;
      const float* xr = x + (size_t)(m0 + row) * XROW;
      const float* gr = gate + (size_t)((m0 + row) >> 5) * DF;
      frag_u f;
#pragma unroll
      for (int j = 0; j < 8; j++) {
        int gk = gk0 + j;
        f.us[j] = (gk < DF) ? f2bf(xr[gk] * gr[gk]) : (u16)0;
      }
      *(bf16x8_t*)(As + row * 128 + swz) = f.f;
      bf16x8_t vb = *(const bf16x8_t*)(Bt + (size_t)(n0w + row) * 256 + kt * 64 + c * 8);
      *(bf16x8_t*)(Bs + row * 128 + swz) = vb;
    }
    __syncthreads();
    bf16x8_t Af[2][4], Bf[2][4];
#pragma unroll
    for (int mi = 0; mi < 4; mi++) {
      int row = wr * 64 + mi * 16 + qi;
      int swz = (row & 7) << 4;
      const unsigned char* ap = As + row * 128;
      Af[0][mi] = *(const bf16x8_t*)(ap + ((g * 16) ^ swz));
      Af[1][mi] = *(const bf16x8_t*)(ap + ((64 + g * 16) ^ swz));
    }
#pragma unroll
    for (int ni = 0; ni < 4; ni++) {
      int row = wc * 64 + ni * 16 + qi;
      int swz = (row & 7) << 4;
      const unsigned char* bp = Bs + row * 128;
      Bf[0][ni] = *(const bf16x8_t*)(bp + ((g * 16) ^ swz));
      Bf[1][ni] = *(const bf16x8_t*)(bp + ((64 + g * 16) ^ swz));
    }
#pragma unroll
    for (int ks = 0; ks < 2; ks++)
#pragma unroll
      for (int mi = 0; mi < 4; mi++)
#pragma unroll
        for (int ni = 0; ni < 4; ni++)
          acc[mi][ni] = __builtin_amdgcn_mfma_f32_16x16x32_bf16(Af[ks][mi], Bf[ks][ni], acc[mi][ni], 0, 0, 0);
  }
#pragma unroll
  for (int mi = 0; mi < 4; mi++) {
#pragma unroll
    for (int ni = 0; ni < 4; ni++) {
#pragma unroll
      for (int r = 0; r < 4; r++) {
        int row = m0 + wr * 64 + mi * 16 + 4 * g + r;
        int col = n0w + wc * 64 + ni * 16 + qi;
        C[(size_t)row * 256 + col] = acc[mi][ni][r] + bias[col] + pe[(row & (T0 - 1)) * DM + col];
      }
    }
  }
}

// ---------------- fus GEMM: fused = pooled @ fus_W + fus_b ----------------
__global__ __launch_bounds__(256) void k_fus(const u16* __restrict__ A, const u16* __restrict__ Bt,
                                             const float* __restrict__ bias, float* __restrict__ C) {
  __shared__ __align__(16) unsigned char sm[16384];
  unsigned char* As = sm;
  unsigned char* Bs = sm + 8192;
  int n0 = blockIdx.x * 64, m0 = blockIdx.y * 64;
  int tid = threadIdx.x, lane = tid & 63, wid = tid >> 6;
  int qi = lane & 15, g = lane >> 4;
  f32x4_t acc[4];
#pragma unroll
  for (int i = 0; i < 4; i++) acc[i] = (f32x4_t){0.f, 0.f, 0.f, 0.f};
  for (int kt = 0; kt < 12; kt++) {
    if (kt) __syncthreads();
#pragma unroll
    for (int i = 0; i < 2; i++) {
      int cid = tid + i * 256;
      int row = cid >> 3, c = cid & 7;
      int swz = (c * 16) ^ ((row & 7) << 4);
      *(bf16x8_t*)(As + row * 128 + swz) = *(const bf16x8_t*)(A + (size_t)(m0 + row) * 768 + kt * 64 + c * 8);
      *(bf16x8_t*)(Bs + row * 128 + swz) = *(const bf16x8_t*)(Bt + (size_t)(n0 + row) * 768 + kt * 64 + c * 8);
    }
    __syncthreads();
    int arow = wid * 16 + qi;
    int asw = (arow & 7) << 4;
    bf16x8_t Af0 = *(const bf16x8_t*)(As + arow * 128 + ((g * 16) ^ asw));
    bf16x8_t Af1 = *(const bf16x8_t*)(As + arow * 128 + ((64 + g * 16) ^ asw));
#pragma unroll
    for (int ni = 0; ni < 4; ni++) {
      int brow = ni * 16 + qi;
      int bsw = (brow & 7) << 4;
      bf16x8_t B0 = *(const bf16x8_t*)(Bs + brow * 128 + ((g * 16) ^ bsw));
      bf16x8_t B1 = *(const bf16x8_t*)(Bs + brow * 128 + ((64 + g * 16) ^ bsw));
      acc[ni] = __builtin_amdgcn_mfma_f32_16x16x32_bf16(Af0, B0, acc[ni], 0, 0, 0);
      acc[ni] = __builtin_amdgcn_mfma_f32_16x16x32_bf16(Af1, B1, acc[ni], 0, 0, 0);
    }
  }
#pragma unroll
  for (int ni = 0; ni < 4; ni++)
#pragma unroll
    for (int r = 0; r < 4; r++) {
      int row = m0 + wid * 16 + 4 * g + r;
      int col = n0 + ni * 16 + qi;
      C[(size_t)row * 256 + col] = acc[ni][r] + bias[col];
    }
}

// ---------------- LayerNorm: wave per row, 4 rows/block ----------------
template <bool RES, bool ABF>
__global__ __launch_bounds__(256) void k_ln(const void* __restrict__ a, const float* __restrict__ b,
                                            const float* __restrict__ g, const float* __restrict__ be,
                                            u16* __restrict__ out) {
  int row = blockIdx.x * 4 + (threadIdx.x >> 6);
  int lane = threadIdx.x & 63;
  size_t base = (size_t)row * DM + lane * 4;
  float v[4];
  if (ABF) {
    ushort4 u = *(const ushort4*)((const u16*)a + base);
    v[0] = bf2f(u.x); v[1] = bf2f(u.y); v[2] = bf2f(u.z); v[3] = bf2f(u.w);
  } else {
    f32x4_t t = *(const f32x4_t*)((const float*)a + base);
    v[0] = t[0]; v[1] = t[1]; v[2] = t[2]; v[3] = t[3];
  }
  if (RES) {
    f32x4_t t = *(const f32x4_t*)(b + base);
    v[0] += t[0]; v[1] += t[1]; v[2] += t[2]; v[3] += t[3];
  }
  float s = v[0] + v[1] + v[2] + v[3];
#pragma unroll
  for (int off = 1; off < 64; off <<= 1) s += __shfl_xor(s, off);
  float mean = s * (1.0f / DM);
  float d0 = v[0] - mean, d1 = v[1] - mean, d2 = v[2] - mean, d3 = v[3] - mean;
  float ss = d0 * d0 + d1 * d1 + d2 * d2 + d3 * d3;
#pragma unroll
  for (int off = 1; off < 64; off <<= 1) ss += __shfl_xor(ss, off);
  float inv = rsqrtf(ss * (1.0f / DM) + 1e-5f);
  f32x4_t gg = *(const f32x4_t*)(g + lane * 4);
  f32x4_t bb = *(const f32x4_t*)(be + lane * 4);
  ushort4 o4;
  o4.x = f2bf(d0 * inv * gg[0] + bb[0]);
  o4.y = f2bf(d1 * inv * gg[1] + bb[1]);
  o4.z = f2bf(d2 * inv * gg[2] + bb[2]);
  o4.w = f2bf(d3 * inv * gg[3] + bb[3]);
  *(ushort4*)(out + base) = o4;
}

// ---------------- mean-pool over time groups, both scales in one dispatch (bf16 out) ----------------
// mid: 16384 rows -> out rows [0,16384); small: 8192 rows -> out rows [16384,24576)
__global__ void k_poolmean(const float* __restrict__ h, u16* __restrict__ out) {
  int bid = blockIdx.x;
  int Tout, P, obase;
  if (bid < 4096) { Tout = 16; P = 2; obase = 0; }
  else { Tout = 8; P = 4; obase = 16384; bid -= 4096; }
  int vi = bid * 256 + threadIdx.x;
  int dv = vi & 63;
  int rowi = vi >> 6;
  int to = rowi % Tout;
  int n = rowi / Tout;
  int Tin = Tout * P;
  float s0 = 0.f, s1 = 0.f, s2 = 0.f, s3 = 0.f;
  for (int p = 0; p < P; p++) {
    f32x4_t t = *(const f32x4_t*)(h + ((size_t)(n * Tin + to * P + p)) * DM + dv * 4);
    s0 += t[0]; s1 += t[1]; s2 += t[2]; s3 += t[3];
  }
  float inv = 1.0f / (float)P;
  ushort4 o4;
  o4.x = f2bf(s0 * inv); o4.y = f2bf(s1 * inv); o4.z = f2bf(s2 * inv); o4.w = f2bf(s3 * inv);
  *(ushort4*)(out + (size_t)(obase + rowi) * DM + dv * 4) = o4;
}

// ---------------- time attention via MFMA + FUSED residual+LN epilogue; exp2-space softmax ----------------
template <int T>
__global__ __launch_bounds__(256) void k_tattn(const u16* __restrict__ q, const u16* __restrict__ k,
                                               const u16* __restrict__ v, u16* __restrict__ xn,
                                               const float* __restrict__ g2, const float* __restrict__ b2) {
  constexpr int TR = (T < 16) ? 16 : T;
  constexpr int QKB = TR * 128;
  constexpr int HS = 2 * QKB + 64 * 80;
  __shared__ __align__(16) unsigned char smem[4 * HS];  // >= T*260*4 for all T
  int n = blockIdx.x;
  int tid = threadIdx.x, lane = tid & 63, h = tid >> 6;
  int qi = lane & 15, g = lane >> 4;
  unsigned char* Qs = smem + h * HS;
  unsigned char* Ks = Qs + QKB;
  unsigned char* Vt = Ks + QKB;

  const u16* qh = q + (size_t)n * T * 256 + h * 64;
  const u16* kh = k + (size_t)n * T * 256 + h * 64;
  const u16* vh = v + (size_t)n * T * 256 + h * 64;
  const bf16x8_t zero8 = {0, 0, 0, 0, 0, 0, 0, 0};

  for (int idx = lane; idx < TR * 8; idx += 64) {
    int row = idx >> 3, c = idx & 7;
    bf16x8_t vq = zero8, vk = zero8;
    if (row < T) {
      vq = *(const bf16x8_t*)(qh + (size_t)row * 256 + c * 8);
      vk = *(const bf16x8_t*)(kh + (size_t)row * 256 + c * 8);
    }
    int off = row * 128 + ((c * 16) ^ ((row & 7) << 4));
    *(bf16x8_t*)(Qs + off) = vq;
    *(bf16x8_t*)(Ks + off) = vk;
  }
  // V staged transposed with sigma-permuted key positions
  {
    int kp = lane & 15, dg = lane >> 4;
    int d0 = dg * 16;
    int kk = 2 * kp;
    int cb = ((((kk >> 2) & 3) << 3) | (((kk >> 4) & 1) << 2) | (kk & 3)) * 2;
    frag_u a0, a1, b0, b1;
    a0.f = a1.f = b0.f = b1.f = zero8;
    if (kk < T) {
      a0.f = *(const bf16x8_t*)(vh + (size_t)kk * 256 + d0);
      a1.f = *(const bf16x8_t*)(vh + (size_t)kk * 256 + d0 + 8);
    }
    if (kk + 1 < T) {
      b0.f = *(const bf16x8_t*)(vh + (size_t)(kk + 1) * 256 + d0);
      b1.f = *(const bf16x8_t*)(vh + (size_t)(kk + 1) * 256 + d0 + 8);
    }
#pragma unroll
    for (int i = 0; i < 8; i++)
      *(unsigned int*)(Vt + (d0 + i) * 80 + cb) = (unsigned int)a0.us[i] | ((unsigned int)b0.us[i] << 16);
#pragma unroll
    for (int i = 0; i < 8; i++)
      *(unsigned int*)(Vt + (d0 + 8 + i) * 80 + cb) = (unsigned int)a1.us[i] | ((unsigned int)b1.us[i] << 16);
  }
  __syncthreads();

  constexpr int NQT = (T == 32) ? 2 : 1;
  constexpr int NSUB = (T == 32) ? 2 : 1;

  bf16x8_t Qb[NQT][2];
#pragma unroll
  for (int qt = 0; qt < NQT; qt++) {
    int row = qt * 16 + qi;
    int sw = (row & 7) << 4;
#pragma unroll
    for (int kst = 0; kst < 2; kst++)
      Qb[qt][kst] = *(const bf16x8_t*)(Qs + row * 128 + ((kst * 64 + g * 16) ^ sw));
  }
  f32x4_t sacc[NQT][NSUB];
#pragma unroll
  for (int qt = 0; qt < NQT; qt++)
#pragma unroll
    for (int sub = 0; sub < NSUB; sub++) sacc[qt][sub] = (f32x4_t){0.f, 0.f, 0.f, 0.f};
  __builtin_amdgcn_s_setprio(1);
#pragma unroll
  for (int sub = 0; sub < NSUB; sub++) {
    int row = sub * 16 + qi;
    int sw = (row & 7) << 4;
    bf16x8_t Ka[2];
#pragma unroll
    for (int kst = 0; kst < 2; kst++)
      Ka[kst] = *(const bf16x8_t*)(Ks + row * 128 + ((kst * 64 + g * 16) ^ sw));
#pragma unroll
    for (int qt = 0; qt < NQT; qt++)
#pragma unroll
      for (int kst = 0; kst < 2; kst++)
        sacc[qt][sub] = __builtin_amdgcn_mfma_f32_16x16x32_bf16(Ka[kst], Qb[qt][kst], sacc[qt][sub], 0, 0, 0);
  }
  __builtin_amdgcn_s_setprio(0);
  // softmax (exp2-space; Q pre-scaled); P packed in-register (sigma layout)
  frag_u Pf[NQT];
#pragma unroll
  for (int qt = 0; qt < NQT; qt++) {
    float sv[NSUB][4];
    float mx = -3.0e38f;
#pragma unroll
    for (int sub = 0; sub < NSUB; sub++)
#pragma unroll
      for (int r = 0; r < 4; r++) {
        int key = sub * 16 + 4 * g + r;
        float s = sacc[qt][sub][r];
        if (key >= T) s = -3.0e38f;
        sv[sub][r] = s;
        mx = fmaxf(mx, s);
      }
    mx = fmaxf(mx, __shfl_xor(mx, 16));
    mx = fmaxf(mx, __shfl_xor(mx, 32));
    float p[NSUB][4];
    float l = 0.f;
#pragma unroll
    for (int sub = 0; sub < NSUB; sub++)
#pragma unroll
      for (int r = 0; r < 4; r++) {
        float e = exp2f(sv[sub][r] - mx);
        p[sub][r] = e;
        l += e;
      }
    l += __shfl_xor(l, 16);
    l += __shfl_xor(l, 32);
    float linv = 1.0f / l;
    Pf[qt].u32[0] = cvtpk(p[0][0] * linv, p[0][1] * linv);
    Pf[qt].u32[1] = cvtpk(p[0][2] * linv, p[0][3] * linv);
    if (NSUB == 2) {
      Pf[qt].u32[2] = cvtpk(p[NSUB - 1][0] * linv, p[NSUB - 1][1] * linv);
      Pf[qt].u32[3] = cvtpk(p[NSUB - 1][2] * linv, p[NSUB - 1][3] * linv);
    } else {
      Pf[qt].u32[2] = 0u;
      Pf[qt].u32[3] = 0u;
    }
  }
  // PV
  f32x4_t oacc[NQT][4];
#pragma unroll
  for (int qt = 0; qt < NQT; qt++)
#pragma unroll
    for (int ni = 0; ni < 4; ni++) oacc[qt][ni] = (f32x4_t){0.f, 0.f, 0.f, 0.f};
  __builtin_amdgcn_s_setprio(1);
#pragma unroll
  for (int ni = 0; ni < 4; ni++) {
    bf16x8_t Vb = *(const bf16x8_t*)(Vt + (ni * 16 + qi) * 80 + g * 16);
#pragma unroll
    for (int qt = 0; qt < NQT; qt++)
      oacc[qt][ni] = __builtin_amdgcn_mfma_f32_16x16x32_bf16(Pf[qt].f, Vb, oacc[qt][ni], 0, 0, 0);
  }
  __builtin_amdgcn_s_setprio(0);

  // ---- fused residual + LN: stage o to LDS fp32, xt = LN(xn + o) -> xn in-place ----
  __syncthreads();  // all Q/K/V LDS reads done; safe to repurpose smem
  float* oL = (float*)smem;  // [T][260] fp32
#pragma unroll
  for (int qt = 0; qt < NQT; qt++)
#pragma unroll
    for (int ni = 0; ni < 4; ni++)
#pragma unroll
      for (int r = 0; r < 4; r++) {
        int qq = qt * 16 + 4 * g + r;
        if (qq < T) oL[qq * 260 + h * 64 + ni * 16 + qi] = oacc[qt][ni][r];
      }
  __syncthreads();
  for (int row = h; row < T; row += 4) {
    size_t base = ((size_t)(n * T + row)) * 256 + lane * 4;
    f32x4_t ov = *(const f32x4_t*)(oL + row * 260 + lane * 4);
    ushort4 xu = *(const ushort4*)(xn + base);
    float v0 = ov[0] + bf2f(xu.x);
    float v1 = ov[1] + bf2f(xu.y);
    float v2 = ov[2] + bf2f(xu.z);
    float v3 = ov[3] + bf2f(xu.w);
    float s = v0 + v1 + v2 + v3;
#pragma unroll
    for (int off = 1; off < 64; off <<= 1) s += __shfl_xor(s, off);
    float mean = s * (1.0f / DM);
    float d0 = v0 - mean, d1 = v1 - mean, d2 = v2 - mean, d3 = v3 - mean;
    float ss = d0 * d0 + d1 * d1 + d2 * d2 + d3 * d3;
#pragma unroll
    for (int off = 1; off < 64; off <<= 1) ss += __shfl_xor(ss, off);
    float inv = rsqrtf(ss * (1.0f / DM) + 1e-5f);
    f32x4_t gg = *(const f32x4_t*)(g2 + lane * 4);
    f32x4_t bb = *(const f32x4_t*)(b2 + lane * 4);
    ushort4 o4;
    o4.x = f2bf(d0 * inv * gg[0] + bb[0]);
    o4.y = f2bf(d1 * inv * gg[1] + bb[1]);
    o4.z = f2bf(d2 * inv * gg[2] + bb[2]);
    o4.w = f2bf(d3 * inv * gg[3] + bb[3]);
    *(ushort4*)(xn + base) = o4;
  }
}

// ---------------- stock attention (round-9 proven): 32 q/wave, sigma-PV, defer-max, exp2 ----------------
__global__ __launch_bounds__(256) void k_sattn(const u16* __restrict__ q, const u16* __restrict__ k,
                                               const u16* __restrict__ v, float* __restrict__ o) {
  __shared__ __align__(16) unsigned char smem[32768];
  unsigned char* Ks = smem;
  unsigned char* Vt = smem + 16384;

  int bid = blockIdx.x;
  int T, rowbase;
  if (bid < 512) { T = 32; rowbase = 0; }
  else if (bid < 768) { T = 16; rowbase = B1R; bid -= 512; }
  else { T = 8; rowbase = B2R; bid -= 768; }
  const int NTH = T * 2;
  int xcd = bid & 7, slot = bid >> 3;
  int th = xcd * (NTH >> 3) + (slot >> 3);
  int qb = slot & 7;
  int t = th >> 1, h = th & 1;

  int tid = threadIdx.x;
  int lane = tid & 63;
  int wid = tid >> 6;
  int qi = lane & 15;
  int g = lane >> 4;

  const size_t rs = (size_t)T * 256;
  const size_t hb = (size_t)rowbase * 256 + (size_t)t * 256 + h * 128;
  const u16* qp = q + hb;
  const u16* kp = k + hb;
  const u16* vp = v + hb;
  float* op = o + hb;

  int q0 = qb * 128 + wid * 32;

  bf16x8_t QfA[4], QfB[4];
  {
    const u16* sA = qp + (size_t)(q0 + qi) * rs + g * 8;
    const u16* sB = sA + 16 * rs;
#pragma unroll
    for (int kst = 0; kst < 4; kst++) {
      QfA[kst] = *(const bf16x8_t*)(sA + kst * 32);
      QfB[kst] = *(const bf16x8_t*)(sB + kst * 32);
    }
  }

  f32x4_t OA[8], OB[8];
#pragma unroll
  for (int i = 0; i < 8; i++) {
    OA[i] = (f32x4_t){0.f, 0.f, 0.f, 0.f};
    OB[i] = (f32x4_t){0.f, 0.f, 0.f, 0.f};
  }
  float mA = -3.0e38f, lA = 0.f, mB = -3.0e38f, lB = 0.f;

  // sigma position for V staging (constant per thread)
  int kpair = tid & 31, dg = tid >> 5;
  int d0s = dg * 16;
  int kk = 2 * kpair;
  int cb = (((kk >> 5) << 5) | (((kk >> 2) & 3) << 3) | (((kk >> 4) & 1) << 2) | (kk & 3)) * 2;

  for (int kb = 0; kb < NS; kb += 64) {
    __syncthreads();
    // stage K tile (swizzled rows)
#pragma unroll
    for (int i = 0; i < 4; i++) {
      int cid = tid + i * 256;
      int row = cid >> 4, ch = cid & 15;
      bf16x8_t kv = *(const bf16x8_t*)(kp + (size_t)(kb + row) * rs + ch * 8);
      *(bf16x8_t*)(Ks + row * 256 + ((ch * 16) ^ ((row & 7) << 4))) = kv;
    }
    // stage V transposed, sigma-permuted key columns
    {
      const u16* s0 = vp + (size_t)(kb + kk) * rs + d0s;
      const u16* s1 = s0 + rs;
      frag_u a0, a1, b0, b1;
      a0.f = *(const bf16x8_t*)s0;
      a1.f = *(const bf16x8_t*)(s0 + 8);
      b0.f = *(const bf16x8_t*)s1;
      b1.f = *(const bf16x8_t*)(s1 + 8);
#pragma unroll
      for (int i = 0; i < 8; i++) {
        int d = d0s + i;
        *(unsigned int*)(Vt + d * 128 + (cb ^ ((d & 7) << 4))) =
            (unsigned int)a0.us[i] | ((unsigned int)b0.us[i] << 16);
      }
#pragma unroll
      for (int i = 0; i < 8; i++) {
        int d = d0s + 8 + i;
        *(unsigned int*)(Vt + d * 128 + (cb ^ ((d & 7) << 4))) =
            (unsigned int)a1.us[i] | ((unsigned int)b1.us[i] << 16);
      }
    }
    __syncthreads();

    // QK^T (swapped) for both query groups; K A-frags read once
    f32x4_t saA[4], saB[4];
#pragma unroll
    for (int i = 0; i < 4; i++) {
      saA[i] = (f32x4_t){0.f, 0.f, 0.f, 0.f};
      saB[i] = (f32x4_t){0.f, 0.f, 0.f, 0.f};
    }
    __builtin_amdgcn_s_setprio(1);
#pragma unroll
    for (int sub = 0; sub < 4; sub++) {
      int row = sub * 16 + qi;
      int swz = (row & 7) << 4;
      const unsigned char* kr = Ks + row * 256;
#pragma unroll
      for (int kst = 0; kst < 4; kst++) {
        bf16x8_t Af = *(const bf16x8_t*)(kr + ((g * 16 + kst * 64) ^ swz));
        saA[sub] = __builtin_amdgcn_mfma_f32_16x16x32_bf16(Af, QfA[kst], saA[sub], 0, 0, 0);
        saB[sub] = __builtin_amdgcn_mfma_f32_16x16x32_bf16(Af, QfB[kst], saB[sub], 0, 0, 0);
      }
    }
    __builtin_amdgcn_s_setprio(0);

    float pmA = -3.0e38f, pmB = -3.0e38f;
#pragma unroll
    for (int sub = 0; sub < 4; sub++)
#pragma unroll
      for (int r = 0; r < 4; r++) {
        pmA = fmaxf(pmA, saA[sub][r]);
        pmB = fmaxf(pmB, saB[sub][r]);
      }
    pmA = fmaxf(pmA, __shfl_xor(pmA, 16));
    pmA = fmaxf(pmA, __shfl_xor(pmA, 32));
    pmB = fmaxf(pmB, __shfl_xor(pmB, 16));
    pmB = fmaxf(pmB, __shfl_xor(pmB, 32));
    // defer-max (T13): rescale only when max grew past threshold (11.5 in log2 ~ e^8)
    if (__any(fmaxf(pmA - mA, pmB - mB) > 11.5f)) {
      float mnA = fmaxf(mA, pmA), mnB = fmaxf(mB, pmB);
      float fA = exp2f(mA - mnA), fB = exp2f(mB - mnB);
      lA *= fA;
      lB *= fB;
      float frA[4], frB[4];
#pragma unroll
      for (int r = 0; r < 4; r++) {
        frA[r] = __shfl(fA, (g << 2) | r);
        frB[r] = __shfl(fB, (g << 2) | r);
      }
#pragma unroll
      for (int dsub = 0; dsub < 8; dsub++)
#pragma unroll
        for (int r = 0; r < 4; r++) {
          OA[dsub][r] *= frA[r];
          OB[dsub][r] *= frB[r];
        }
      mA = mnA;
      mB = mnB;
    }
    float pA[4][4], pB[4][4];
    float lsA = 0.f, lsB = 0.f;
#pragma unroll
    for (int sub = 0; sub < 4; sub++)
#pragma unroll
      for (int r = 0; r < 4; r++) {
        float eA = exp2f(saA[sub][r] - mA);
        float eB = exp2f(saB[sub][r] - mB);
        pA[sub][r] = eA;
        pB[sub][r] = eB;
        lsA += eA;
        lsB += eB;
      }
    lsA += __shfl_xor(lsA, 16);
    lsA += __shfl_xor(lsA, 32);
    lsB += __shfl_xor(lsB, 16);
    lsB += __shfl_xor(lsB, 32);
    lA += lsA;
    lB += lsB;

    // P A-fragments lane-local via sigma: Pa[kst] slot e = p[2kst + (e>>2)][e&3]
    frag_u fA0, fA1, fB0, fB1;
    fA0.u32[0] = cvtpk(pA[0][0], pA[0][1]);
    fA0.u32[1] = cvtpk(pA[0][2], pA[0][3]);
    fA0.u32[2] = cvtpk(pA[1][0], pA[1][1]);
    fA0.u32[3] = cvtpk(pA[1][2], pA[1][3]);
    fA1.u32[0] = cvtpk(pA[2][0], pA[2][1]);
    fA1.u32[1] = cvtpk(pA[2][2], pA[2][3]);
    fA1.u32[2] = cvtpk(pA[3][0], pA[3][1]);
    fA1.u32[3] = cvtpk(pA[3][2], pA[3][3]);
    fB0.u32[0] = cvtpk(pB[0][0], pB[0][1]);
    fB0.u32[1] = cvtpk(pB[0][2], pB[0][3]);
    fB0.u32[2] = cvtpk(pB[1][0], pB[1][1]);
    fB0.u32[3] = cvtpk(pB[1][2], pB[1][3]);
    fB1.u32[0] = cvtpk(pB[2][0], pB[2][1]);
    fB1.u32[1] = cvtpk(pB[2][2], pB[2][3]);
    fB1.u32[2] = cvtpk(pB[3][0], pB[3][1]);
    fB1.u32[3] = cvtpk(pB[3][2], pB[3][3]);

    __builtin_amdgcn_s_setprio(1);
#pragma unroll
    for (int kst = 0; kst < 2; kst++) {
      bf16x8_t PaA = kst ? fA1.f : fA0.f;
      bf16x8_t PaB = kst ? fB1.f : fB0.f;
#pragma unroll
      for (int dsub = 0; dsub < 8; dsub++) {
        int row = dsub * 16 + qi;
        bf16x8_t Vb = *(const bf16x8_t*)(Vt + row * 128 + ((g * 16 + kst * 64) ^ ((row & 7) << 4)));
        OA[dsub] = __builtin_amdgcn_mfma_f32_16x16x32_bf16(PaA, Vb, OA[dsub], 0, 0, 0);
        OB[dsub] = __builtin_amdgcn_mfma_f32_16x16x32_bf16(PaB, Vb, OB[dsub], 0, 0, 0);
      }
    }
    __builtin_amdgcn_s_setprio(0);
  }

  float rinA[4], rinB[4];
#pragma unroll
  for (int r = 0; r < 4; r++) {
    rinA[r] = 1.0f / __shfl(lA, (g << 2) | r);
    rinB[r] = 1.0f / __shfl(lB, (g << 2) | r);
  }
#pragma unroll
  for (int dsub = 0; dsub < 8; dsub++)
#pragma unroll
    for (int r = 0; r < 4; r++) {
      size_t rowA = (size_t)(q0 + 4 * g + r);
      op[rowA * rs + dsub * 16 + qi] = OA[dsub][r] * rinA[r];
      op[(rowA + 16) * rs + dsub * 16 + qi] = OB[dsub][r] * rinB[r];
    }
}

// ---------------- temporal pooling, all 3 scales in one dispatch ----------------
__global__ __launch_bounds__(256) void k_tpool(const float* __restrict__ hh, const u16* __restrict__ z,
                                               u16* __restrict__ pooled) {
  int bid = blockIdx.x;
  int T, rowbase, off;
  if (bid < 1024) { T = 32; rowbase = 0; off = 0; }
  else if (bid < 2048) { T = 16; rowbase = B1R; off = 256; bid -= 1024; }
  else { T = 8; rowbase = B2R; off = 512; bid -= 2048; }
  int n = bid;
  int tid = threadIdx.x, lane = tid & 63, w = tid >> 6;
  __shared__ float lam[T0];
  __shared__ float lame[T0];
  __shared__ float lsum;
  const float* hn = hh + ((size_t)rowbase + (size_t)n * T) * DM;
  f32x4_t last = *(const f32x4_t*)(hn + (size_t)(T - 1) * DM + lane * 4);
  for (int t = w; t < T; t += 4) {
    f32x4_t hv = *(const f32x4_t*)(hn + (size_t)t * DM + lane * 4);
    float s = hv[0] * last[0] + hv[1] * last[1] + hv[2] * last[2] + hv[3] * last[3];
#pragma unroll
    for (int o2 = 1; o2 < 64; o2 <<= 1) s += __shfl_xor(s, o2);
    if (lane == 0) lam[t] = s;
  }
  __syncthreads();
  if (tid < 64) {
    float vv = (lane < T) ? lam[lane] : -3.0e38f;
    float mx = vv;
#pragma unroll
    for (int o2 = 1; o2 < 64; o2 <<= 1) mx = fmaxf(mx, __shfl_xor(mx, o2));
    float e = (lane < T) ? expf(vv - mx) : 0.f;
    float su = e;
#pragma unroll
    for (int o2 = 1; o2 < 64; o2 <<= 1) su += __shfl_xor(su, o2);
    if (lane < T) lame[lane] = e;
    if (lane == 0) lsum = su;
  }
  __syncthreads();
  float acc = 0.f;
  const u16* zn = z + ((size_t)rowbase + (size_t)n * T) * DM + tid;
  for (int t = 0; t < T; t++) acc += lame[t] * bf2f(zn[(size_t)t * DM]);
  pooled[(size_t)n * 768 + off + tid] = f2bf(acc / lsum);
}

// ---------------- final ----------------
__global__ __launch_bounds__(256) void k_final(const float* __restrict__ f, const float* __restrict__ g,
                                               const float* __restrict__ b, const float* __restrict__ dw,
                                               const float* __restrict__ db, float* __restrict__ out) {
  int n = blockIdx.x, d = threadIdx.x;
  float v = f[(size_t)n * DM + d];
  __shared__ float red[256];
  red[d] = v;
  __syncthreads();
  for (int s = 128; s > 0; s >>= 1) { if (d < s) red[d] += red[d + s]; __syncthreads(); }
  float mean = red[0] * (1.0f / DM);
  __syncthreads();
  float dv = v - mean;
  red[d] = dv * dv;
  __syncthreads();
  for (int s = 128; s > 0; s >>= 1) { if (d < s) red[d] += red[d + s]; __syncthreads(); }
  float var = red[0] * (1.0f / DM);
  __syncthreads();
  float y = dv * rsqrtf(var + 1e-5f) * g[d] + b[d];
  y = fmaxf(y, 0.f);
  red[d] = y * dw[d];
  __syncthreads();
  for (int s = 128; s > 0; s >>= 1) { if (d < s) red[d] += red[d + s]; __syncthreads(); }
  if (d == 0) out[n] = red[0] + db[0];
}

extern "C" void kernel_launch(void* const* d_in, const int* in_sizes, int n_in,
                              void* d_out, int out_size, void* d_ws, size_t ws_size,
                              hipStream_t stream) {
  const float* x = (const float*)d_in[0];
  const float* gate_W = (const float*)d_in[1];
  const float* gate_b = (const float*)d_in[2];
  const float* feat_W = (const float*)d_in[3];
  const float* feat_b = (const float*)d_in[4];
  const float* ds_mid_W = (const float*)d_in[5];
  const float* ds_mid_b = (const float*)d_in[6];
  const float* ds_small_W = (const float*)d_in[7];
  const float* ds_small_b = (const float*)d_in[8];
  const float* tn1g = (const float*)d_in[9];
  const float* tn1b = (const float*)d_in[10];
  const float* tWq = (const float*)d_in[11];
  const float* tWk = (const float*)d_in[12];
  const float* tWv = (const float*)d_in[13];
  const float* tn2g = (const float*)d_in[14];
  const float* tn2b = (const float*)d_in[15];
  const float* tW1 = (const float*)d_in[16];
  const float* tb1 = (const float*)d_in[17];
  const float* tW2 = (const float*)d_in[18];
  const float* tb2 = (const float*)d_in[19];
  const float* sn1g = (const float*)d_in[20];
  const float* sn1b = (const float*)d_in[21];
  const float* sWq = (const float*)d_in[22];
  const float* sWk = (const float*)d_in[23];
  const float* sWv = (const float*)d_in[24];
  const float* sn2g = (const float*)d_in[25];
  const float* sn2b = (const float*)d_in[26];
  const float* sW1 = (const float*)d_in[27];
  const float* sb1 = (const float*)d_in[28];
  const float* sW2 = (const float*)d_in[29];
  const float* sb2 = (const float*)d_in[30];
  const float* temp_W = (const float*)d_in[31];
  const float* fus_W = (const float*)d_in[32];
  const float* fus_b = (const float*)d_in[33];
  const float* fus_g = (const float*)d_in[34];
  const float* fus_bb = (const float*)d_in[35];
  const float* dec_W = (const float*)d_in[36];
  const float* dec_b = (const float*)d_in[37];

  float* ws = (float*)d_ws;
  size_t o = 0;
  float* pe = ws + o; o += 8192;
  float* g = ws + o; o += 161792;
  u16* wt = (u16*)(ws + o); o += 458752;        // 14 x 256x256 bf16
  float* hcat = ws + o; o += (size_t)MTOT * 256;     // fp32 slab: h -> bO -> hh -> fused
  u16* bXNu = (u16*)(ws + o); o += (size_t)MTOT * 128;
  u16* bQu = (u16*)(ws + o); o += (size_t)MTOT * 128;
  u16* bKu = (u16*)(ws + o); o += (size_t)MTOT * 128;
  u16* bVu = (u16*)(ws + o); o += (size_t)MTOT * 128;
  float* bO = hcat;
  float* hh = hcat;
  float* fused = hcat;
  u16* pooledu = bXNu;   // alias: xn2 dead before tpool
  u16* wFus = bKu;       // alias: written by wtrans after bKu dead

  u16* wFeat = wt;
  u16* wDSm = wt + 1 * 65536;
  u16* wDSs = wt + 2 * 65536;
  u16* wTQ = wt + 3 * 65536;
  u16* wTK = wt + 4 * 65536;
  u16* wTV = wt + 5 * 65536;
  u16* wT1 = wt + 6 * 65536;
  u16* wT2 = wt + 7 * 65536;
  u16* wSQ = wt + 8 * 65536;
  u16* wSK = wt + 9 * 65536;
  u16* wSV = wt + 10 * 65536;
  u16* wS1 = wt + 11 * 65536;
  u16* wS2 = wt + 12 * 65536;
  u16* wTW = wt + 13 * 65536;

  k_pe<<<T0, DM, 0, stream>>>(pe);
  k_gate<<<NS, 256, 0, stream>>>(x, gate_W, gate_b, g);
  WPrep wp;
  wp.s[0] = feat_W; wp.s[1] = ds_mid_W; wp.s[2] = ds_small_W;
  wp.s[3] = tWq; wp.s[4] = tWk; wp.s[5] = tWv; wp.s[6] = tW1; wp.s[7] = tW2;
  wp.s[8] = sWq; wp.s[9] = sWk; wp.s[10] = sWv; wp.s[11] = sW1; wp.s[12] = sW2;
  wp.s[13] = temp_W;
  for (int i = 0; i < 14; i++) wp.sc[i] = 1.0f;
  wp.sc[3] = 0.125f * 1.4426950408889634f;                 // tWq: 1/sqrt(64) * log2(e)
  wp.sc[8] = 0.08838834764831845f * 1.4426950408889634f;   // sWq: 1/sqrt(128) * log2(e)
  k_wprep<<<224, 256, 0, stream>>>(wp, wt);

  // h0 (rows 0..32767)
  k_fgemm<<<dim3(2, 256), 256, 0, stream>>>(x, g, wFeat, feat_b, pe, hcat);
  // both pools in one dispatch: mid -> bQu rows [0,16384), small -> bQu rows [16384,24576)
  k_poolmean<<<6144, 256, 0, stream>>>(hcat, bQu);
  k_bgemm<true, false, false, false><<<dim3(2, 128, 1), 256, 0, stream>>>(
      bQu, wDSm, wDSm, wDSm, ds_mid_b, nullptr, hcat + (size_t)B1R * 256, nullptr, nullptr);
  k_bgemm<true, false, false, false><<<dim3(2, 64, 1), 256, 0, stream>>>(
      bQu + (size_t)16384 * 256, wDSs, wDSs, wDSs, ds_small_b, nullptr,
      hcat + (size_t)B2R * 256, nullptr, nullptr);

  dim3 g1(2, MTOT / 128, 1), g3(2, MTOT / 128, 3);
  // ---- time attention block (all scales merged); LN2 fused into tattn ----
  k_ln<false, false><<<MTOT / 4, 256, 0, stream>>>(hcat, nullptr, tn1g, tn1b, bXNu);
  k_bgemm<false, false, false, true><<<g3, 256, 0, stream>>>(
      bXNu, wTQ, wTK, wTV, nullptr, nullptr, bQu, bKu, bVu);
  k_tattn<32><<<NS, 256, 0, stream>>>(bQu, bKu, bVu, bXNu, tn2g, tn2b);
  k_tattn<16><<<NS, 256, 0, stream>>>(bQu + (size_t)B1R * 256, bKu + (size_t)B1R * 256,
                                      bVu + (size_t)B1R * 256, bXNu + (size_t)B1R * 256, tn2g, tn2b);
  k_tattn<8><<<NS, 256, 0, stream>>>(bQu + (size_t)B2R * 256, bKu + (size_t)B2R * 256,
                                     bVu + (size_t)B2R * 256, bXNu + (size_t)B2R * 256, tn2g, tn2b);
  // bXNu now holds xt
  k_bgemm<true, true, false, true><<<g1, 256, 0, stream>>>(
      bXNu, wT1, wT1, wT1, tb1, nullptr, bKu, nullptr, nullptr);
  k_bgemm<true, false, true, true><<<g1, 256, 0, stream>>>(
      bKu, wT2, wT2, wT2, tb2, bXNu, bVu, nullptr, nullptr);  // z -> bVu
  // ---- stock attention block ----
  k_ln<false, true><<<MTOT / 4, 256, 0, stream>>>(bVu, nullptr, sn1g, sn1b, bXNu);  // xn2
  k_bgemm<false, false, false, true><<<g3, 256, 0, stream>>>(
      bXNu, wSQ, wSK, wSV, nullptr, nullptr, bQu, bKu, bVu);
  k_sattn<<<896, 256, 0, stream>>>(bQu, bKu, bVu, bO);
  k_ln<true, true><<<MTOT / 4, 256, 0, stream>>>(bXNu, bO, sn2g, sn2b, bQu);  // xt2
  k_bgemm<true, true, false, true><<<g1, 256, 0, stream>>>(
      bQu, wS1, wS1, wS1, sb1, nullptr, bKu, nullptr, nullptr);
  k_bgemm<true, false, true, true><<<g1, 256, 0, stream>>>(
      bKu, wS2, wS2, wS2, sb2, bQu, bVu, nullptr, nullptr);  // z2 -> bVu
  k_bgemm<false, false, false, false><<<g1, 256, 0, stream>>>(
      bVu, wTW, wTW, wTW, nullptr, nullptr, hh, nullptr, nullptr);
  k_tpool<<<3072, 256, 0, stream>>>(hh, bVu, pooledu);

  k_wtrans<<<dim3(12, 4), 256, 0, stream>>>(fus_W, wFus);
  k_fus<<<dim3(4, 16), 256, 0, stream>>>(pooledu, wFus, fus_b, fused);
  k_final<<<NS, 256, 0, stream>>>(fused, fus_g, fus_bb, dec_W, dec_b, (float*)d_out);
}

// Round 14
// 487.137 us; speedup vs baseline: 1.1334x; 1.1334x over previous
//
#include <hip/hip_runtime.h>
#include <math.h>

#define NS 1024
#define T0 32
#define DF 158
#define DG 63
#define DM 256
#define XROW (DF + DG)  // 221
// merged-scale row bases: h0 rows [0,32768), h1 [32768,49152), h2 [49152,57344)
#define MTOT 57344
#define B1R 32768
#define B2R 49152

typedef unsigned short u16;
typedef __attribute__((ext_vector_type(8))) short bf16x8_t;
typedef __attribute__((ext_vector_type(4))) float f32x4_t;

union frag_u {
  bf16x8_t f;
  unsigned short us[8];
  unsigned int u32[4];
};

__device__ inline unsigned short f2bf(float x) {
  unsigned int u = __float_as_uint(x);
  unsigned int r = u + 0x7fffu + ((u >> 16) & 1u);
  return (unsigned short)(r >> 16);
}
__device__ inline float bf2f(u16 u) {
  return __uint_as_float(((unsigned int)u) << 16);
}
// v_cvt_pk_bf16_f32: D.lo16 = bf16(a), D.hi16 = bf16(b)
__device__ inline unsigned int cvtpk(float a, float b) {
  unsigned int r;
  asm("v_cvt_pk_bf16_f32 %0, %1, %2" : "=v"(r) : "v"(a), "v"(b));
  return r;
}
// async global->LDS, 16B per lane; LDS dest must be lane-linear (wave-uniform base + lane*16)
__device__ inline void gl16(const u16* gp, unsigned char* lp) {
  __builtin_amdgcn_global_load_lds((const __attribute__((address_space(1))) unsigned int*)gp,
                                   (__attribute__((address_space(3))) unsigned int*)lp, 16, 0, 0);
}

// ---------------- positional encoding table (32 x 256) ----------------
__global__ void k_pe(float* __restrict__ pe) {
  int t = blockIdx.x, d = threadIdx.x;
  int i2 = d & ~1;
  float div = expf((float)i2 * (-logf(10000.0f) / (float)DM));
  float ang = (float)t * div;
  pe[t * DM + d] = (d & 1) ? cosf(ang) : sinf(ang);
}

// ---------------- gate ----------------
__global__ void k_gate(const float* __restrict__ x, const float* __restrict__ gW,
                       const float* __restrict__ gb, float* __restrict__ g) {
  int n = blockIdx.x, tid = threadIdx.x;
  __shared__ float gin[DG];
  __shared__ float red[256];
  if (tid < DG) gin[tid] = x[(size_t)n * T0 * XROW + 31 * XROW + DF + tid];
  __syncthreads();
  float myv = 0.f;
  if (tid < DF) {
    float acc = gb[tid];
    for (int j = 0; j < DG; j++) acc = fmaf(gin[j], gW[j * DF + tid], acc);
    myv = acc * (1.0f / 5.0f);
  }
  red[tid] = (tid < DF) ? myv : -1e30f;
  __syncthreads();
  for (int s = 128; s > 0; s >>= 1) { if (tid < s) red[tid] = fmaxf(red[tid], red[tid + s]); __syncthreads(); }
  float mx = red[0];
  __syncthreads();
  float e = (tid < DF) ? expf(myv - mx) : 0.f;
  red[tid] = e;
  __syncthreads();
  for (int s = 128; s > 0; s >>= 1) { if (tid < s) red[tid] += red[tid + s]; __syncthreads(); }
  float sum = red[0];
  if (tid < DF) g[(size_t)n * DF + tid] = (float)DF * e / sum;
}

// ---------------- weight prep: W[K][256] fp32 -> Wt[256][256] bf16 (transposed, scaled, zero-pad K) ----------------
struct WPrep { const float* s[14]; float sc[14]; };
__global__ __launch_bounds__(256) void k_wprep(WPrep w, u16* __restrict__ dst) {
  int mat = blockIdx.x >> 4, nb = blockIdx.x & 15;
  int tid = threadIdx.x;
  int n = nb * 16 + (tid >> 4);
  int kc = (tid & 15) * 16;
  const float* src = w.s[mat];
  float sc = w.sc[mat];
  int K = (mat == 0) ? DF : 256;
  frag_u f0, f1;
#pragma unroll
  for (int j = 0; j < 8; j++) {
    int k0 = kc + j, k1 = kc + 8 + j;
    f0.us[j] = (k0 < K) ? f2bf(src[(size_t)k0 * 256 + n] * sc) : (u16)0;
    f1.us[j] = (k1 < K) ? f2bf(src[(size_t)k1 * 256 + n] * sc) : (u16)0;
  }
  u16* d = dst + (size_t)mat * 65536 + (size_t)n * 256 + kc;
  *(bf16x8_t*)d = f0.f;
  *(bf16x8_t*)(d + 8) = f1.f;
}

// ---------------- fus_W transpose: [768][256] fp32 -> [256][768] bf16 ----------------
__global__ __launch_bounds__(256) void k_wtrans(const float* __restrict__ W, u16* __restrict__ Wt) {
  __shared__ u16 Ts[64][65];
  int k0 = blockIdx.x * 64, n0 = blockIdx.y * 64;
  int tid = threadIdx.x;
#pragma unroll
  for (int i = 0; i < 16; i++) {
    int e = tid + i * 256;
    int r = e >> 6, c = e & 63;
    Ts[r][c] = f2bf(W[(size_t)(k0 + r) * 256 + n0 + c]);
  }
  __syncthreads();
#pragma unroll
  for (int i = 0; i < 16; i++) {
    int e = tid + i * 256;
    int r = e >> 6, c = e & 63;
    Wt[(size_t)(n0 + r) * 768 + k0 + c] = Ts[c][r];
  }
}

// ---------------- bf16 MFMA GEMM (round-6 proven): gl16 staging, 32KB LDS ----------------
template <bool BIAS, bool RELU, bool RES, bool OUTBF>
__global__ __launch_bounds__(256) void k_bgemm(
    const u16* __restrict__ A,
    const u16* __restrict__ B0, const u16* __restrict__ B1, const u16* __restrict__ B2,
    const float* __restrict__ bias, const u16* __restrict__ res,
    void* __restrict__ C0, void* __restrict__ C1, void* __restrict__ C2) {
  __shared__ __align__(16) unsigned char sm[32768];
  unsigned char* As = sm;
  unsigned char* Bs = sm + 16384;
  const u16* Bt = blockIdx.z == 0 ? B0 : (blockIdx.z == 1 ? B1 : B2);
  void* Cv = blockIdx.z == 0 ? C0 : (blockIdx.z == 1 ? C1 : C2);
  int m0 = blockIdx.y * 128, n0w = blockIdx.x * 128;
  int tid = threadIdx.x, lane = tid & 63, wid = tid >> 6;
  int qi = lane & 15, g = lane >> 4;
  int wr = wid >> 1, wc = wid & 1;
  f32x4_t acc[4][4];
#pragma unroll
  for (int i = 0; i < 4; i++)
#pragma unroll
    for (int j = 0; j < 4; j++) acc[i][j] = (f32x4_t){0.f, 0.f, 0.f, 0.f};
  for (int kt = 0; kt < 4; kt++) {
    if (kt) __syncthreads();
    // stage via global_load_lds: LDS lane-linear, global source pre-swizzled (c^(row&7))
#pragma unroll
    for (int i = 0; i < 4; i++) {
      int cid = tid + i * 256;
      int row = cid >> 3, c = cid & 7;
      int cs = c ^ (row & 7);
      gl16(A + (size_t)(m0 + row) * 256 + kt * 64 + cs * 8, As + cid * 16);
      gl16(Bt + (size_t)(n0w + row) * 256 + kt * 64 + cs * 8, Bs + cid * 16);
    }
    __syncthreads();
    bf16x8_t Af[2][4], Bf[2][4];
#pragma unroll
    for (int mi = 0; mi < 4; mi++) {
      int row = wr * 64 + mi * 16 + qi;
      int swz = (row & 7) << 4;
      const unsigned char* ap = As + row * 128;
      Af[0][mi] = *(const bf16x8_t*)(ap + ((g * 16) ^ swz));
      Af[1][mi] = *(const bf16x8_t*)(ap + ((64 + g * 16) ^ swz));
    }
#pragma unroll
    for (int ni = 0; ni < 4; ni++) {
      int row = wc * 64 + ni * 16 + qi;
      int swz = (row & 7) << 4;
      const unsigned char* bp = Bs + row * 128;
      Bf[0][ni] = *(const bf16x8_t*)(bp + ((g * 16) ^ swz));
      Bf[1][ni] = *(const bf16x8_t*)(bp + ((64 + g * 16) ^ swz));
    }
#pragma unroll
    for (int ks = 0; ks < 2; ks++)
#pragma unroll
      for (int mi = 0; mi < 4; mi++)
#pragma unroll
        for (int ni = 0; ni < 4; ni++)
          acc[mi][ni] = __builtin_amdgcn_mfma_f32_16x16x32_bf16(Af[ks][mi], Bf[ks][ni], acc[mi][ni], 0, 0, 0);
  }
#pragma unroll
  for (int mi = 0; mi < 4; mi++) {
#pragma unroll
    for (int ni = 0; ni < 4; ni++) {
#pragma unroll
      for (int r = 0; r < 4; r++) {
        int row = m0 + wr * 64 + mi * 16 + 4 * g + r;
        int col = n0w + wc * 64 + ni * 16 + qi;
        float vv = acc[mi][ni][r];
        if (BIAS) vv += bias[col];
        if (RES) vv += bf2f(res[(size_t)row * 256 + col]);
        if (RELU) vv = fmaxf(vv, 0.f);
        if (OUTBF) ((u16*)Cv)[(size_t)row * 256 + col] = f2bf(vv);
        else ((float*)Cv)[(size_t)row * 256 + col] = vv;
      }
    }
  }
}

// ---------------- feat GEMM: h = (x*gate)@feat_W + bias + pe, fp32 out ----------------
__global__ __launch_bounds__(256) void k_fgemm(
    const float* __restrict__ x, const float* __restrict__ gate,
    const u16* __restrict__ Bt, const float* __restrict__ bias,
    const float* __restrict__ pe, float* __restrict__ C) {
  __shared__ __align__(16) unsigned char sm[32768];
  unsigned char* As = sm;
  unsigned char* Bs = sm + 16384;
  int m0 = blockIdx.y * 128, n0w = blockIdx.x * 128;
  int tid = threadIdx.x, lane = tid & 63, wid = tid >> 6;
  int qi = lane & 15, g = lane >> 4;
  int wr = wid >> 1, wc = wid & 1;
  f32x4_t acc[4][4];
#pragma unroll
  for (int i = 0; i < 4; i++)
#pragma unroll
    for (int j = 0; j < 4; j++) acc[i][j] = (f32x4_t){0.f, 0.f, 0.f, 0.f};
  for (int kt = 0; kt < 3; kt++) {
    if (kt) __syncthreads();
#pragma unroll
    for (int i = 0; i < 4; i++) {
      int cid = tid + i * 256;
      int row = cid >> 3, c = cid & 7;
      int swz = (c * 16) ^ ((row & 7) << 4);
      int gk0 = kt * 64 + c * 8;
      const float* xr = x + (size_t)(m0 + row) * XROW;
      const float* gr = gate + (size_t)((m0 + row) >> 5) * DF;
      frag_u f;
#pragma unroll
      for (int j = 0; j < 8; j++) {
        int gk = gk0 + j;
        f.us[j] = (gk < DF) ? f2bf(xr[gk] * gr[gk]) : (u16)0;
      }
      *(bf16x8_t*)(As + row * 128 + swz) = f.f;
      bf16x8_t vb = *(const bf16x8_t*)(Bt + (size_t)(n0w + row) * 256 + kt * 64 + c * 8);
      *(bf16x8_t*)(Bs + row * 128 + swz) = vb;
    }
    __syncthreads();
    bf16x8_t Af[2][4], Bf[2][4];
#pragma unroll
    for (int mi = 0; mi < 4; mi++) {
      int row = wr * 64 + mi * 16 + qi;
      int swz = (row & 7) << 4;
      const unsigned char* ap = As + row * 128;
      Af[0][mi] = *(const bf16x8_t*)(ap + ((g * 16) ^ swz));
      Af[1][mi] = *(const bf16x8_t*)(ap + ((64 + g * 16) ^ swz));
    }
#pragma unroll
    for (int ni = 0; ni < 4; ni++) {
      int row = wc * 64 + ni * 16 + qi;
      int swz = (row & 7) << 4;
      const unsigned char* bp = Bs + row * 128;
      Bf[0][ni] = *(const bf16x8_t*)(bp + ((g * 16) ^ swz));
      Bf[1][ni] = *(const bf16x8_t*)(bp + ((64 + g * 16) ^ swz));
    }
#pragma unroll
    for (int ks = 0; ks < 2; ks++)
#pragma unroll
      for (int mi = 0; mi < 4; mi++)
#pragma unroll
        for (int ni = 0; ni < 4; ni++)
          acc[mi][ni] = __builtin_amdgcn_mfma_f32_16x16x32_bf16(Af[ks][mi], Bf[ks][ni], acc[mi][ni], 0, 0, 0);
  }
#pragma unroll
  for (int mi = 0; mi < 4; mi++) {
#pragma unroll
    for (int ni = 0; ni < 4; ni++) {
#pragma unroll
      for (int r = 0; r < 4; r++) {
        int row = m0 + wr * 64 + mi * 16 + 4 * g + r;
        int col = n0w + wc * 64 + ni * 16 + qi;
        C[(size_t)row * 256 + col] = acc[mi][ni][r] + bias[col] + pe[(row & (T0 - 1)) * DM + col];
      }
    }
  }
}

// ---------------- fus GEMM: fused = pooled @ fus_W + fus_b ----------------
__global__ __launch_bounds__(256) void k_fus(const u16* __restrict__ A, const u16* __restrict__ Bt,
                                             const float* __restrict__ bias, float* __restrict__ C) {
  __shared__ __align__(16) unsigned char sm[16384];
  unsigned char* As = sm;
  unsigned char* Bs = sm + 8192;
  int n0 = blockIdx.x * 64, m0 = blockIdx.y * 64;
  int tid = threadIdx.x, lane = tid & 63, wid = tid >> 6;
  int qi = lane & 15, g = lane >> 4;
  f32x4_t acc[4];
#pragma unroll
  for (int i = 0; i < 4; i++) acc[i] = (f32x4_t){0.f, 0.f, 0.f, 0.f};
  for (int kt = 0; kt < 12; kt++) {
    if (kt) __syncthreads();
#pragma unroll
    for (int i = 0; i < 2; i++) {
      int cid = tid + i * 256;
      int row = cid >> 3, c = cid & 7;
      int swz = (c * 16) ^ ((row & 7) << 4);
      *(bf16x8_t*)(As + row * 128 + swz) = *(const bf16x8_t*)(A + (size_t)(m0 + row) * 768 + kt * 64 + c * 8);
      *(bf16x8_t*)(Bs + row * 128 + swz) = *(const bf16x8_t*)(Bt + (size_t)(n0 + row) * 768 + kt * 64 + c * 8);
    }
    __syncthreads();
    int arow = wid * 16 + qi;
    int asw = (arow & 7) << 4;
    bf16x8_t Af0 = *(const bf16x8_t*)(As + arow * 128 + ((g * 16) ^ asw));
    bf16x8_t Af1 = *(const bf16x8_t*)(As + arow * 128 + ((64 + g * 16) ^ asw));
#pragma unroll
    for (int ni = 0; ni < 4; ni++) {
      int brow = ni * 16 + qi;
      int bsw = (brow & 7) << 4;
      bf16x8_t B0 = *(const bf16x8_t*)(Bs + brow * 128 + ((g * 16) ^ bsw));
      bf16x8_t B1 = *(const bf16x8_t*)(Bs + brow * 128 + ((64 + g * 16) ^ bsw));
      acc[ni] = __builtin_amdgcn_mfma_f32_16x16x32_bf16(Af0, B0, acc[ni], 0, 0, 0);
      acc[ni] = __builtin_amdgcn_mfma_f32_16x16x32_bf16(Af1, B1, acc[ni], 0, 0, 0);
    }
  }
#pragma unroll
  for (int ni = 0; ni < 4; ni++)
#pragma unroll
    for (int r = 0; r < 4; r++) {
      int row = m0 + wid * 16 + 4 * g + r;
      int col = n0 + ni * 16 + qi;
      C[(size_t)row * 256 + col] = acc[ni][r] + bias[col];
    }
}

// ---------------- LayerNorm: wave per row, 4 rows/block ----------------
template <bool RES, bool ABF>
__global__ __launch_bounds__(256) void k_ln(const void* __restrict__ a, const float* __restrict__ b,
                                            const float* __restrict__ g, const float* __restrict__ be,
                                            u16* __restrict__ out) {
  int row = blockIdx.x * 4 + (threadIdx.x >> 6);
  int lane = threadIdx.x & 63;
  size_t base = (size_t)row * DM + lane * 4;
  float v[4];
  if (ABF) {
    ushort4 u = *(const ushort4*)((const u16*)a + base);
    v[0] = bf2f(u.x); v[1] = bf2f(u.y); v[2] = bf2f(u.z); v[3] = bf2f(u.w);
  } else {
    f32x4_t t = *(const f32x4_t*)((const float*)a + base);
    v[0] = t[0]; v[1] = t[1]; v[2] = t[2]; v[3] = t[3];
  }
  if (RES) {
    f32x4_t t = *(const f32x4_t*)(b + base);
    v[0] += t[0]; v[1] += t[1]; v[2] += t[2]; v[3] += t[3];
  }
  float s = v[0] + v[1] + v[2] + v[3];
#pragma unroll
  for (int off = 1; off < 64; off <<= 1) s += __shfl_xor(s, off);
  float mean = s * (1.0f / DM);
  float d0 = v[0] - mean, d1 = v[1] - mean, d2 = v[2] - mean, d3 = v[3] - mean;
  float ss = d0 * d0 + d1 * d1 + d2 * d2 + d3 * d3;
#pragma unroll
  for (int off = 1; off < 64; off <<= 1) ss += __shfl_xor(ss, off);
  float inv = rsqrtf(ss * (1.0f / DM) + 1e-5f);
  f32x4_t gg = *(const f32x4_t*)(g + lane * 4);
  f32x4_t bb = *(const f32x4_t*)(be + lane * 4);
  ushort4 o4;
  o4.x = f2bf(d0 * inv * gg[0] + bb[0]);
  o4.y = f2bf(d1 * inv * gg[1] + bb[1]);
  o4.z = f2bf(d2 * inv * gg[2] + bb[2]);
  o4.w = f2bf(d3 * inv * gg[3] + bb[3]);
  *(ushort4*)(out + base) = o4;
}

// ---------------- mean-pool over time groups, both scales in one dispatch (bf16 out) ----------------
// mid: 16384 rows -> out rows [0,16384); small: 8192 rows -> out rows [16384,24576)
__global__ void k_poolmean(const float* __restrict__ h, u16* __restrict__ out) {
  int bid = blockIdx.x;
  int Tout, P, obase;
  if (bid < 4096) { Tout = 16; P = 2; obase = 0; }
  else { Tout = 8; P = 4; obase = 16384; bid -= 4096; }
  int vi = bid * 256 + threadIdx.x;
  int dv = vi & 63;
  int rowi = vi >> 6;
  int to = rowi % Tout;
  int n = rowi / Tout;
  int Tin = Tout * P;
  float s0 = 0.f, s1 = 0.f, s2 = 0.f, s3 = 0.f;
  for (int p = 0; p < P; p++) {
    f32x4_t t = *(const f32x4_t*)(h + ((size_t)(n * Tin + to * P + p)) * DM + dv * 4);
    s0 += t[0]; s1 += t[1]; s2 += t[2]; s3 += t[3];
  }
  float inv = 1.0f / (float)P;
  ushort4 o4;
  o4.x = f2bf(s0 * inv); o4.y = f2bf(s1 * inv); o4.z = f2bf(s2 * inv); o4.w = f2bf(s3 * inv);
  *(ushort4*)(out + (size_t)(obase + rowi) * DM + dv * 4) = o4;
}

// ---------------- time attention via MFMA + FUSED residual+LN epilogue; exp2-space softmax ----------------
template <int T>
__global__ __launch_bounds__(256) void k_tattn(const u16* __restrict__ q, const u16* __restrict__ k,
                                               const u16* __restrict__ v, u16* __restrict__ xn,
                                               const float* __restrict__ g2, const float* __restrict__ b2) {
  constexpr int TR = (T < 16) ? 16 : T;
  constexpr int QKB = TR * 128;
  constexpr int HS = 2 * QKB + 64 * 80;
  __shared__ __align__(16) unsigned char smem[4 * HS];  // >= T*260*4 for all T
  int n = blockIdx.x;
  int tid = threadIdx.x, lane = tid & 63, h = tid >> 6;
  int qi = lane & 15, g = lane >> 4;
  unsigned char* Qs = smem + h * HS;
  unsigned char* Ks = Qs + QKB;
  unsigned char* Vt = Ks + QKB;

  const u16* qh = q + (size_t)n * T * 256 + h * 64;
  const u16* kh = k + (size_t)n * T * 256 + h * 64;
  const u16* vh = v + (size_t)n * T * 256 + h * 64;
  const bf16x8_t zero8 = {0, 0, 0, 0, 0, 0, 0, 0};

  for (int idx = lane; idx < TR * 8; idx += 64) {
    int row = idx >> 3, c = idx & 7;
    bf16x8_t vq = zero8, vk = zero8;
    if (row < T) {
      vq = *(const bf16x8_t*)(qh + (size_t)row * 256 + c * 8);
      vk = *(const bf16x8_t*)(kh + (size_t)row * 256 + c * 8);
    }
    int off = row * 128 + ((c * 16) ^ ((row & 7) << 4));
    *(bf16x8_t*)(Qs + off) = vq;
    *(bf16x8_t*)(Ks + off) = vk;
  }
  // V staged transposed with sigma-permuted key positions
  {
    int kp = lane & 15, dg = lane >> 4;
    int d0 = dg * 16;
    int kk = 2 * kp;
    int cb = ((((kk >> 2) & 3) << 3) | (((kk >> 4) & 1) << 2) | (kk & 3)) * 2;
    frag_u a0, a1, b0, b1;
    a0.f = a1.f = b0.f = b1.f = zero8;
    if (kk < T) {
      a0.f = *(const bf16x8_t*)(vh + (size_t)kk * 256 + d0);
      a1.f = *(const bf16x8_t*)(vh + (size_t)kk * 256 + d0 + 8);
    }
    if (kk + 1 < T) {
      b0.f = *(const bf16x8_t*)(vh + (size_t)(kk + 1) * 256 + d0);
      b1.f = *(const bf16x8_t*)(vh + (size_t)(kk + 1) * 256 + d0 + 8);
    }
#pragma unroll
    for (int i = 0; i < 8; i++)
      *(unsigned int*)(Vt + (d0 + i) * 80 + cb) = (unsigned int)a0.us[i] | ((unsigned int)b0.us[i] << 16);
#pragma unroll
    for (int i = 0; i < 8; i++)
      *(unsigned int*)(Vt + (d0 + 8 + i) * 80 + cb) = (unsigned int)a1.us[i] | ((unsigned int)b1.us[i] << 16);
  }
  __syncthreads();

  constexpr int NQT = (T == 32) ? 2 : 1;
  constexpr int NSUB = (T == 32) ? 2 : 1;

  bf16x8_t Qb[NQT][2];
#pragma unroll
  for (int qt = 0; qt < NQT; qt++) {
    int row = qt * 16 + qi;
    int sw = (row & 7) << 4;
#pragma unroll
    for (int kst = 0; kst < 2; kst++)
      Qb[qt][kst] = *(const bf16x8_t*)(Qs + row * 128 + ((kst * 64 + g * 16) ^ sw));
  }
  f32x4_t sacc[NQT][NSUB];
#pragma unroll
  for (int qt = 0; qt < NQT; qt++)
#pragma unroll
    for (int sub = 0; sub < NSUB; sub++) sacc[qt][sub] = (f32x4_t){0.f, 0.f, 0.f, 0.f};
#pragma unroll
  for (int sub = 0; sub < NSUB; sub++) {
    int row = sub * 16 + qi;
    int sw = (row & 7) << 4;
    bf16x8_t Ka[2];
#pragma unroll
    for (int kst = 0; kst < 2; kst++)
      Ka[kst] = *(const bf16x8_t*)(Ks + row * 128 + ((kst * 64 + g * 16) ^ sw));
#pragma unroll
    for (int qt = 0; qt < NQT; qt++)
#pragma unroll
      for (int kst = 0; kst < 2; kst++)
        sacc[qt][sub] = __builtin_amdgcn_mfma_f32_16x16x32_bf16(Ka[kst], Qb[qt][kst], sacc[qt][sub], 0, 0, 0);
  }
  // softmax (exp2-space; Q pre-scaled); P packed in-register (sigma layout)
  frag_u Pf[NQT];
#pragma unroll
  for (int qt = 0; qt < NQT; qt++) {
    float sv[NSUB][4];
    float mx = -3.0e38f;
#pragma unroll
    for (int sub = 0; sub < NSUB; sub++)
#pragma unroll
      for (int r = 0; r < 4; r++) {
        int key = sub * 16 + 4 * g + r;
        float s = sacc[qt][sub][r];
        if (key >= T) s = -3.0e38f;
        sv[sub][r] = s;
        mx = fmaxf(mx, s);
      }
    mx = fmaxf(mx, __shfl_xor(mx, 16));
    mx = fmaxf(mx, __shfl_xor(mx, 32));
    float p[NSUB][4];
    float l = 0.f;
#pragma unroll
    for (int sub = 0; sub < NSUB; sub++)
#pragma unroll
      for (int r = 0; r < 4; r++) {
        float e = exp2f(sv[sub][r] - mx);
        p[sub][r] = e;
        l += e;
      }
    l += __shfl_xor(l, 16);
    l += __shfl_xor(l, 32);
    float linv = 1.0f / l;
    Pf[qt].u32[0] = cvtpk(p[0][0] * linv, p[0][1] * linv);
    Pf[qt].u32[1] = cvtpk(p[0][2] * linv, p[0][3] * linv);
    if (NSUB == 2) {
      Pf[qt].u32[2] = cvtpk(p[NSUB - 1][0] * linv, p[NSUB - 1][1] * linv);
      Pf[qt].u32[3] = cvtpk(p[NSUB - 1][2] * linv, p[NSUB - 1][3] * linv);
    } else {
      Pf[qt].u32[2] = 0u;
      Pf[qt].u32[3] = 0u;
    }
  }
  // PV
  f32x4_t oacc[NQT][4];
#pragma unroll
  for (int qt = 0; qt < NQT; qt++)
#pragma unroll
    for (int ni = 0; ni < 4; ni++) oacc[qt][ni] = (f32x4_t){0.f, 0.f, 0.f, 0.f};
#pragma unroll
  for (int ni = 0; ni < 4; ni++) {
    bf16x8_t Vb = *(const bf16x8_t*)(Vt + (ni * 16 + qi) * 80 + g * 16);
#pragma unroll
    for (int qt = 0; qt < NQT; qt++)
      oacc[qt][ni] = __builtin_amdgcn_mfma_f32_16x16x32_bf16(Pf[qt].f, Vb, oacc[qt][ni], 0, 0, 0);
  }

  // ---- fused residual + LN: stage o to LDS fp32, xt = LN(xn + o) -> xn in-place ----
  __syncthreads();  // all Q/K/V LDS reads done; safe to repurpose smem
  float* oL = (float*)smem;  // [T][260] fp32
#pragma unroll
  for (int qt = 0; qt < NQT; qt++)
#pragma unroll
    for (int ni = 0; ni < 4; ni++)
#pragma unroll
      for (int r = 0; r < 4; r++) {
        int qq = qt * 16 + 4 * g + r;
        if (qq < T) oL[qq * 260 + h * 64 + ni * 16 + qi] = oacc[qt][ni][r];
      }
  __syncthreads();
  for (int row = h; row < T; row += 4) {
    size_t base = ((size_t)(n * T + row)) * 256 + lane * 4;
    f32x4_t ov = *(const f32x4_t*)(oL + row * 260 + lane * 4);
    ushort4 xu = *(const ushort4*)(xn + base);
    float v0 = ov[0] + bf2f(xu.x);
    float v1 = ov[1] + bf2f(xu.y);
    float v2 = ov[2] + bf2f(xu.z);
    float v3 = ov[3] + bf2f(xu.w);
    float s = v0 + v1 + v2 + v3;
#pragma unroll
    for (int off = 1; off < 64; off <<= 1) s += __shfl_xor(s, off);
    float mean = s * (1.0f / DM);
    float d0 = v0 - mean, d1 = v1 - mean, d2 = v2 - mean, d3 = v3 - mean;
    float ss = d0 * d0 + d1 * d1 + d2 * d2 + d3 * d3;
#pragma unroll
    for (int off = 1; off < 64; off <<= 1) ss += __shfl_xor(ss, off);
    float inv = rsqrtf(ss * (1.0f / DM) + 1e-5f);
    f32x4_t gg = *(const f32x4_t*)(g2 + lane * 4);
    f32x4_t bb = *(const f32x4_t*)(b2 + lane * 4);
    ushort4 o4;
    o4.x = f2bf(d0 * inv * gg[0] + bb[0]);
    o4.y = f2bf(d1 * inv * gg[1] + bb[1]);
    o4.z = f2bf(d2 * inv * gg[2] + bb[2]);
    o4.w = f2bf(d3 * inv * gg[3] + bb[3]);
    *(ushort4*)(xn + base) = o4;
  }
}

// ---------------- stock attention (round-9 proven): 32 q/wave, sigma-PV, defer-max, exp2 ----------------
__global__ __launch_bounds__(256) void k_sattn(const u16* __restrict__ q, const u16* __restrict__ k,
                                               const u16* __restrict__ v, float* __restrict__ o) {
  __shared__ __align__(16) unsigned char smem[32768];
  unsigned char* Ks = smem;
  unsigned char* Vt = smem + 16384;

  int bid = blockIdx.x;
  int T, rowbase;
  if (bid < 512) { T = 32; rowbase = 0; }
  else if (bid < 768) { T = 16; rowbase = B1R; bid -= 512; }
  else { T = 8; rowbase = B2R; bid -= 768; }
  const int NTH = T * 2;
  int xcd = bid & 7, slot = bid >> 3;
  int th = xcd * (NTH >> 3) + (slot >> 3);
  int qb = slot & 7;
  int t = th >> 1, h = th & 1;

  int tid = threadIdx.x;
  int lane = tid & 63;
  int wid = tid >> 6;
  int qi = lane & 15;
  int g = lane >> 4;

  const size_t rs = (size_t)T * 256;
  const size_t hb = (size_t)rowbase * 256 + (size_t)t * 256 + h * 128;
  const u16* qp = q + hb;
  const u16* kp = k + hb;
  const u16* vp = v + hb;
  float* op = o + hb;

  int q0 = qb * 128 + wid * 32;

  bf16x8_t QfA[4], QfB[4];
  {
    const u16* sA = qp + (size_t)(q0 + qi) * rs + g * 8;
    const u16* sB = sA + 16 * rs;
#pragma unroll
    for (int kst = 0; kst < 4; kst++) {
      QfA[kst] = *(const bf16x8_t*)(sA + kst * 32);
      QfB[kst] = *(const bf16x8_t*)(sB + kst * 32);
    }
  }

  f32x4_t OA[8], OB[8];
#pragma unroll
  for (int i = 0; i < 8; i++) {
    OA[i] = (f32x4_t){0.f, 0.f, 0.f, 0.f};
    OB[i] = (f32x4_t){0.f, 0.f, 0.f, 0.f};
  }
  float mA = -3.0e38f, lA = 0.f, mB = -3.0e38f, lB = 0.f;

  // sigma position for V staging (constant per thread)
  int kpair = tid & 31, dg = tid >> 5;
  int d0s = dg * 16;
  int kk = 2 * kpair;
  int cb = (((kk >> 5) << 5) | (((kk >> 2) & 3) << 3) | (((kk >> 4) & 1) << 2) | (kk & 3)) * 2;

  for (int kb = 0; kb < NS; kb += 64) {
    __syncthreads();
    // stage K tile (swizzled rows)
#pragma unroll
    for (int i = 0; i < 4; i++) {
      int cid = tid + i * 256;
      int row = cid >> 4, ch = cid & 15;
      bf16x8_t kv = *(const bf16x8_t*)(kp + (size_t)(kb + row) * rs + ch * 8);
      *(bf16x8_t*)(Ks + row * 256 + ((ch * 16) ^ ((row & 7) << 4))) = kv;
    }
    // stage V transposed, sigma-permuted key columns
    {
      const u16* s0 = vp + (size_t)(kb + kk) * rs + d0s;
      const u16* s1 = s0 + rs;
      frag_u a0, a1, b0, b1;
      a0.f = *(const bf16x8_t*)s0;
      a1.f = *(const bf16x8_t*)(s0 + 8);
      b0.f = *(const bf16x8_t*)s1;
      b1.f = *(const bf16x8_t*)(s1 + 8);
#pragma unroll
      for (int i = 0; i < 8; i++) {
        int d = d0s + i;
        *(unsigned int*)(Vt + d * 128 + (cb ^ ((d & 7) << 4))) =
            (unsigned int)a0.us[i] | ((unsigned int)b0.us[i] << 16);
      }
#pragma unroll
      for (int i = 0; i < 8; i++) {
        int d = d0s + 8 + i;
        *(unsigned int*)(Vt + d * 128 + (cb ^ ((d & 7) << 4))) =
            (unsigned int)a1.us[i] | ((unsigned int)b1.us[i] << 16);
      }
    }
    __syncthreads();

    // QK^T (swapped) for both query groups; K A-frags read once
    f32x4_t saA[4], saB[4];
#pragma unroll
    for (int i = 0; i < 4; i++) {
      saA[i] = (f32x4_t){0.f, 0.f, 0.f, 0.f};
      saB[i] = (f32x4_t){0.f, 0.f, 0.f, 0.f};
    }
#pragma unroll
    for (int sub = 0; sub < 4; sub++) {
      int row = sub * 16 + qi;
      int swz = (row & 7) << 4;
      const unsigned char* kr = Ks + row * 256;
#pragma unroll
      for (int kst = 0; kst < 4; kst++) {
        bf16x8_t Af = *(const bf16x8_t*)(kr + ((g * 16 + kst * 64) ^ swz));
        saA[sub] = __builtin_amdgcn_mfma_f32_16x16x32_bf16(Af, QfA[kst], saA[sub], 0, 0, 0);
        saB[sub] = __builtin_amdgcn_mfma_f32_16x16x32_bf16(Af, QfB[kst], saB[sub], 0, 0, 0);
      }
    }

    float pmA = -3.0e38f, pmB = -3.0e38f;
#pragma unroll
    for (int sub = 0; sub < 4; sub++)
#pragma unroll
      for (int r = 0; r < 4; r++) {
        pmA = fmaxf(pmA, saA[sub][r]);
        pmB = fmaxf(pmB, saB[sub][r]);
      }
    pmA = fmaxf(pmA, __shfl_xor(pmA, 16));
    pmA = fmaxf(pmA, __shfl_xor(pmA, 32));
    pmB = fmaxf(pmB, __shfl_xor(pmB, 16));
    pmB = fmaxf(pmB, __shfl_xor(pmB, 32));
    // defer-max (T13): rescale only when max grew past threshold (11.5 in log2 ~ e^8)
    if (__any(fmaxf(pmA - mA, pmB - mB) > 11.5f)) {
      float mnA = fmaxf(mA, pmA), mnB = fmaxf(mB, pmB);
      float fA = exp2f(mA - mnA), fB = exp2f(mB - mnB);
      lA *= fA;
      lB *= fB;
      float frA[4], frB[4];
#pragma unroll
      for (int r = 0; r < 4; r++) {
        frA[r] = __shfl(fA, (g << 2) | r);
        frB[r] = __shfl(fB, (g << 2) | r);
      }
#pragma unroll
      for (int dsub = 0; dsub < 8; dsub++)
#pragma unroll
        for (int r = 0; r < 4; r++) {
          OA[dsub][r] *= frA[r];
          OB[dsub][r] *= frB[r];
        }
      mA = mnA;
      mB = mnB;
    }
    float pA[4][4], pB[4][4];
    float lsA = 0.f, lsB = 0.f;
#pragma unroll
    for (int sub = 0; sub < 4; sub++)
#pragma unroll
      for (int r = 0; r < 4; r++) {
        float eA = exp2f(saA[sub][r] - mA);
        float eB = exp2f(saB[sub][r] - mB);
        pA[sub][r] = eA;
        pB[sub][r] = eB;
        lsA += eA;
        lsB += eB;
      }
    lsA += __shfl_xor(lsA, 16);
    lsA += __shfl_xor(lsA, 32);
    lsB += __shfl_xor(lsB, 16);
    lsB += __shfl_xor(lsB, 32);
    lA += lsA;
    lB += lsB;

    // P A-fragments lane-local via sigma: Pa[kst] slot e = p[2kst + (e>>2)][e&3]
    frag_u fA0, fA1, fB0, fB1;
    fA0.u32[0] = cvtpk(pA[0][0], pA[0][1]);
    fA0.u32[1] = cvtpk(pA[0][2], pA[0][3]);
    fA0.u32[2] = cvtpk(pA[1][0], pA[1][1]);
    fA0.u32[3] = cvtpk(pA[1][2], pA[1][3]);
    fA1.u32[0] = cvtpk(pA[2][0], pA[2][1]);
    fA1.u32[1] = cvtpk(pA[2][2], pA[2][3]);
    fA1.u32[2] = cvtpk(pA[3][0], pA[3][1]);
    fA1.u32[3] = cvtpk(pA[3][2], pA[3][3]);
    fB0.u32[0] = cvtpk(pB[0][0], pB[0][1]);
    fB0.u32[1] = cvtpk(pB[0][2], pB[0][3]);
    fB0.u32[2] = cvtpk(pB[1][0], pB[1][1]);
    fB0.u32[3] = cvtpk(pB[1][2], pB[1][3]);
    fB1.u32[0] = cvtpk(pB[2][0], pB[2][1]);
    fB1.u32[1] = cvtpk(pB[2][2], pB[2][3]);
    fB1.u32[2] = cvtpk(pB[3][0], pB[3][1]);
    fB1.u32[3] = cvtpk(pB[3][2], pB[3][3]);

#pragma unroll
    for (int kst = 0; kst < 2; kst++) {
      bf16x8_t PaA = kst ? fA1.f : fA0.f;
      bf16x8_t PaB = kst ? fB1.f : fB0.f;
#pragma unroll
      for (int dsub = 0; dsub < 8; dsub++) {
        int row = dsub * 16 + qi;
        bf16x8_t Vb = *(const bf16x8_t*)(Vt + row * 128 + ((g * 16 + kst * 64) ^ ((row & 7) << 4)));
        OA[dsub] = __builtin_amdgcn_mfma_f32_16x16x32_bf16(PaA, Vb, OA[dsub], 0, 0, 0);
        OB[dsub] = __builtin_amdgcn_mfma_f32_16x16x32_bf16(PaB, Vb, OB[dsub], 0, 0, 0);
      }
    }
  }

  float rinA[4], rinB[4];
#pragma unroll
  for (int r = 0; r < 4; r++) {
    rinA[r] = 1.0f / __shfl(lA, (g << 2) | r);
    rinB[r] = 1.0f / __shfl(lB, (g << 2) | r);
  }
#pragma unroll
  for (int dsub = 0; dsub < 8; dsub++)
#pragma unroll
    for (int r = 0; r < 4; r++) {
      size_t rowA = (size_t)(q0 + 4 * g + r);
      op[rowA * rs + dsub * 16 + qi] = OA[dsub][r] * rinA[r];
      op[(rowA + 16) * rs + dsub * 16 + qi] = OB[dsub][r] * rinB[r];
    }
}

// ---------------- temporal pooling, all 3 scales in one dispatch ----------------
__global__ __launch_bounds__(256) void k_tpool(const float* __restrict__ hh, const u16* __restrict__ z,
                                               u16* __restrict__ pooled) {
  int bid = blockIdx.x;
  int T, rowbase, off;
  if (bid < 1024) { T = 32; rowbase = 0; off = 0; }
  else if (bid < 2048) { T = 16; rowbase = B1R; off = 256; bid -= 1024; }
  else { T = 8; rowbase = B2R; off = 512; bid -= 2048; }
  int n = bid;
  int tid = threadIdx.x, lane = tid & 63, w = tid >> 6;
  __shared__ float lam[T0];
  __shared__ float lame[T0];
  __shared__ float lsum;
  const float* hn = hh + ((size_t)rowbase + (size_t)n * T) * DM;
  f32x4_t last = *(const f32x4_t*)(hn + (size_t)(T - 1) * DM + lane * 4);
  for (int t = w; t < T; t += 4) {
    f32x4_t hv = *(const f32x4_t*)(hn + (size_t)t * DM + lane * 4);
    float s = hv[0] * last[0] + hv[1] * last[1] + hv[2] * last[2] + hv[3] * last[3];
#pragma unroll
    for (int o2 = 1; o2 < 64; o2 <<= 1) s += __shfl_xor(s, o2);
    if (lane == 0) lam[t] = s;
  }
  __syncthreads();
  if (tid < 64) {
    float vv = (lane < T) ? lam[lane] : -3.0e38f;
    float mx = vv;
#pragma unroll
    for (int o2 = 1; o2 < 64; o2 <<= 1) mx = fmaxf(mx, __shfl_xor(mx, o2));
    float e = (lane < T) ? expf(vv - mx) : 0.f;
    float su = e;
#pragma unroll
    for (int o2 = 1; o2 < 64; o2 <<= 1) su += __shfl_xor(su, o2);
    if (lane < T) lame[lane] = e;
    if (lane == 0) lsum = su;
  }
  __syncthreads();
  float acc = 0.f;
  const u16* zn = z + ((size_t)rowbase + (size_t)n * T) * DM + tid;
  for (int t = 0; t < T; t++) acc += lame[t] * bf2f(zn[(size_t)t * DM]);
  pooled[(size_t)n * 768 + off + tid] = f2bf(acc / lsum);
}

// ---------------- final ----------------
__global__ __launch_bounds__(256) void k_final(const float* __restrict__ f, const float* __restrict__ g,
                                               const float* __restrict__ b, const float* __restrict__ dw,
                                               const float* __restrict__ db, float* __restrict__ out) {
  int n = blockIdx.x, d = threadIdx.x;
  float v = f[(size_t)n * DM + d];
  __shared__ float red[256];
  red[d] = v;
  __syncthreads();
  for (int s = 128; s > 0; s >>= 1) { if (d < s) red[d] += red[d + s]; __syncthreads(); }
  float mean = red[0] * (1.0f / DM);
  __syncthreads();
  float dv = v - mean;
  red[d] = dv * dv;
  __syncthreads();
  for (int s = 128; s > 0; s >>= 1) { if (d < s) red[d] += red[d + s]; __syncthreads(); }
  float var = red[0] * (1.0f / DM);
  __syncthreads();
  float y = dv * rsqrtf(var + 1e-5f) * g[d] + b[d];
  y = fmaxf(y, 0.f);
  red[d] = y * dw[d];
  __syncthreads();
  for (int s = 128; s > 0; s >>= 1) { if (d < s) red[d] += red[d + s]; __syncthreads(); }
  if (d == 0) out[n] = red[0] + db[0];
}

extern "C" void kernel_launch(void* const* d_in, const int* in_sizes, int n_in,
                              void* d_out, int out_size, void* d_ws, size_t ws_size,
                              hipStream_t stream) {
  const float* x = (const float*)d_in[0];
  const float* gate_W = (const float*)d_in[1];
  const float* gate_b = (const float*)d_in[2];
  const float* feat_W = (const float*)d_in[3];
  const float* feat_b = (const float*)d_in[4];
  const float* ds_mid_W = (const float*)d_in[5];
  const float* ds_mid_b = (const float*)d_in[6];
  const float* ds_small_W = (const float*)d_in[7];
  const float* ds_small_b = (const float*)d_in[8];
  const float* tn1g = (const float*)d_in[9];
  const float* tn1b = (const float*)d_in[10];
  const float* tWq = (const float*)d_in[11];
  const float* tWk = (const float*)d_in[12];
  const float* tWv = (const float*)d_in[13];
  const float* tn2g = (const float*)d_in[14];
  const float* tn2b = (const float*)d_in[15];
  const float* tW1 = (const float*)d_in[16];
  const float* tb1 = (const float*)d_in[17];
  const float* tW2 = (const float*)d_in[18];
  const float* tb2 = (const float*)d_in[19];
  const float* sn1g = (const float*)d_in[20];
  const float* sn1b = (const float*)d_in[21];
  const float* sWq = (const float*)d_in[22];
  const float* sWk = (const float*)d_in[23];
  const float* sWv = (const float*)d_in[24];
  const float* sn2g = (const float*)d_in[25];
  const float* sn2b = (const float*)d_in[26];
  const float* sW1 = (const float*)d_in[27];
  const float* sb1 = (const float*)d_in[28];
  const float* sW2 = (const float*)d_in[29];
  const float* sb2 = (const float*)d_in[30];
  const float* temp_W = (const float*)d_in[31];
  const float* fus_W = (const float*)d_in[32];
  const float* fus_b = (const float*)d_in[33];
  const float* fus_g = (const float*)d_in[34];
  const float* fus_bb = (const float*)d_in[35];
  const float* dec_W = (const float*)d_in[36];
  const float* dec_b = (const float*)d_in[37];

  float* ws = (float*)d_ws;
  size_t o = 0;
  float* pe = ws + o; o += 8192;
  float* g = ws + o; o += 161792;
  u16* wt = (u16*)(ws + o); o += 458752;        // 14 x 256x256 bf16
  float* hcat = ws + o; o += (size_t)MTOT * 256;     // fp32 slab: h -> bO -> hh -> fused
  u16* bXNu = (u16*)(ws + o); o += (size_t)MTOT * 128;
  u16* bQu = (u16*)(ws + o); o += (size_t)MTOT * 128;
  u16* bKu = (u16*)(ws + o); o += (size_t)MTOT * 128;
  u16* bVu = (u16*)(ws + o); o += (size_t)MTOT * 128;
  float* bO = hcat;
  float* hh = hcat;
  float* fused = hcat;
  u16* pooledu = bXNu;   // alias: xn2 dead before tpool
  u16* wFus = bKu;       // alias: written by wtrans after bKu dead

  u16* wFeat = wt;
  u16* wDSm = wt + 1 * 65536;
  u16* wDSs = wt + 2 * 65536;
  u16* wTQ = wt + 3 * 65536;
  u16* wTK = wt + 4 * 65536;
  u16* wTV = wt + 5 * 65536;
  u16* wT1 = wt + 6 * 65536;
  u16* wT2 = wt + 7 * 65536;
  u16* wSQ = wt + 8 * 65536;
  u16* wSK = wt + 9 * 65536;
  u16* wSV = wt + 10 * 65536;
  u16* wS1 = wt + 11 * 65536;
  u16* wS2 = wt + 12 * 65536;
  u16* wTW = wt + 13 * 65536;

  k_pe<<<T0, DM, 0, stream>>>(pe);
  k_gate<<<NS, 256, 0, stream>>>(x, gate_W, gate_b, g);
  WPrep wp;
  wp.s[0] = feat_W; wp.s[1] = ds_mid_W; wp.s[2] = ds_small_W;
  wp.s[3] = tWq; wp.s[4] = tWk; wp.s[5] = tWv; wp.s[6] = tW1; wp.s[7] = tW2;
  wp.s[8] = sWq; wp.s[9] = sWk; wp.s[10] = sWv; wp.s[11] = sW1; wp.s[12] = sW2;
  wp.s[13] = temp_W;
  for (int i = 0; i < 14; i++) wp.sc[i] = 1.0f;
  wp.sc[3] = 0.125f * 1.4426950408889634f;                 // tWq: 1/sqrt(64) * log2(e)
  wp.sc[8] = 0.08838834764831845f * 1.4426950408889634f;   // sWq: 1/sqrt(128) * log2(e)
  k_wprep<<<224, 256, 0, stream>>>(wp, wt);

  // h0 (rows 0..32767)
  k_fgemm<<<dim3(2, 256), 256, 0, stream>>>(x, g, wFeat, feat_b, pe, hcat);
  // both pools in one dispatch: mid -> bQu rows [0,16384), small -> bQu rows [16384,24576)
  k_poolmean<<<6144, 256, 0, stream>>>(hcat, bQu);
  k_bgemm<true, false, false, false><<<dim3(2, 128, 1), 256, 0, stream>>>(
      bQu, wDSm, wDSm, wDSm, ds_mid_b, nullptr, hcat + (size_t)B1R * 256, nullptr, nullptr);
  k_bgemm<true, false, false, false><<<dim3(2, 64, 1), 256, 0, stream>>>(
      bQu + (size_t)16384 * 256, wDSs, wDSs, wDSs, ds_small_b, nullptr,
      hcat + (size_t)B2R * 256, nullptr, nullptr);

  dim3 g1(2, MTOT / 128, 1), g3(2, MTOT / 128, 3);
  // ---- time attention block (all scales merged); LN2 fused into tattn ----
  k_ln<false, false><<<MTOT / 4, 256, 0, stream>>>(hcat, nullptr, tn1g, tn1b, bXNu);
  k_bgemm<false, false, false, true><<<g3, 256, 0, stream>>>(
      bXNu, wTQ, wTK, wTV, nullptr, nullptr, bQu, bKu, bVu);
  k_tattn<32><<<NS, 256, 0, stream>>>(bQu, bKu, bVu, bXNu, tn2g, tn2b);
  k_tattn<16><<<NS, 256, 0, stream>>>(bQu + (size_t)B1R * 256, bKu + (size_t)B1R * 256,
                                      bVu + (size_t)B1R * 256, bXNu + (size_t)B1R * 256, tn2g, tn2b);
  k_tattn<8><<<NS, 256, 0, stream>>>(bQu + (size_t)B2R * 256, bKu + (size_t)B2R * 256,
                                     bVu + (size_t)B2R * 256, bXNu + (size_t)B2R * 256, tn2g, tn2b);
  // bXNu now holds xt
  k_bgemm<true, true, false, true><<<g1, 256, 0, stream>>>(
      bXNu, wT1, wT1, wT1, tb1, nullptr, bKu, nullptr, nullptr);
  k_bgemm<true, false, true, true><<<g1, 256, 0, stream>>>(
      bKu, wT2, wT2, wT2, tb2, bXNu, bVu, nullptr, nullptr);  // z -> bVu
  // ---- stock attention block ----
  k_ln<false, true><<<MTOT / 4, 256, 0, stream>>>(bVu, nullptr, sn1g, sn1b, bXNu);  // xn2
  k_bgemm<false, false, false, true><<<g3, 256, 0, stream>>>(
      bXNu, wSQ, wSK, wSV, nullptr, nullptr, bQu, bKu, bVu);
  k_sattn<<<896, 256, 0, stream>>>(bQu, bKu, bVu, bO);
  k_ln<true, true><<<MTOT / 4, 256, 0, stream>>>(bXNu, bO, sn2g, sn2b, bQu);  // xt2
  k_bgemm<true, true, false, true><<<g1, 256, 0, stream>>>(
      bQu, wS1, wS1, wS1, sb1, nullptr, bKu, nullptr, nullptr);
  k_bgemm<true, false, true, true><<<g1, 256, 0, stream>>>(
      bKu, wS2, wS2, wS2, sb2, bQu, bVu, nullptr, nullptr);  // z2 -> bVu
  k_bgemm<false, false, false, false><<<g1, 256, 0, stream>>>(
      bVu, wTW, wTW, wTW, nullptr, nullptr, hh, nullptr, nullptr);
  k_tpool<<<3072, 256, 0, stream>>>(hh, bVu, pooledu);

  k_wtrans<<<dim3(12, 4), 256, 0, stream>>>(fus_W, wFus);
  k_fus<<<dim3(4, 16), 256, 0, stream>>>(pooledu, wFus, fus_b, fused);
  k_final<<<NS, 256, 0, stream>>>(fused, fus_g, fus_bb, dec_W, dec_b, (float*)d_out);
}